// Round 1
// baseline (27043.674 us; speedup 1.0000x reference)
//
#include <hip/hip_runtime.h>
#include <math.h>

// ---- problem constants ----
#define B_      64
#define S_      128
#define H_      768
#define L_      6
#define NH_     12
#define DH_     64
#define FF_     3072
#define INTENT_ 22
#define TAGS_   122
#define NT_     (B_*S_)          // 8192 tokens
#define LN_EPS  1e-12f
#define INV_SQRT_DH 0.125f       // 1/sqrt(64)

// ---- GEMM tiling ----
#define BM 64
#define BN 64
#define BK 16

#define GF_RELU_IN  1
#define GF_RELU_OUT 2
#define GF_GELU_OUT 4
#define GF_ACCUM    8

// ===================== block reduction helper (256 thr) =====================
__device__ inline float block_reduce_sum256(float v, float* red) {
    int tid = threadIdx.x;
    red[tid] = v; __syncthreads();
    for (int off = 128; off > 0; off >>= 1) {
        if (tid < off) red[tid] += red[tid + off];
        __syncthreads();
    }
    float r = red[0]; __syncthreads();
    return r;
}

// ===================== embedding + LN =====================
__global__ __launch_bounds__(256) void embed_ln_kernel(
    const int* __restrict__ ids, const float* __restrict__ we,
    const float* __restrict__ pe, const float* __restrict__ gs,
    const float* __restrict__ gb, float* __restrict__ X)
{
    __shared__ float red[256];
    int bs = blockIdx.x;                  // token index
    int sq = bs % S_;
    int id = ids[bs];
    const float* wrow = we + (size_t)id * H_;
    const float* prow = pe + (size_t)sq * H_;
    float z[3];
    #pragma unroll
    for (int r = 0; r < 3; r++) {
        int h = threadIdx.x + 256*r;
        z[r] = wrow[h] + prow[h];
    }
    float sum = z[0] + z[1] + z[2];
    sum = block_reduce_sum256(sum, red);
    float m = sum * (1.0f / H_);
    float vs = 0.f;
    #pragma unroll
    for (int r = 0; r < 3; r++) { float d = z[r]-m; vs += d*d; }
    vs = block_reduce_sum256(vs, red) * (1.0f / H_);
    float rstd = 1.0f / sqrtf(vs + LN_EPS);
    float* out = X + (size_t)bs * H_;
    #pragma unroll
    for (int r = 0; r < 3; r++) {
        int h = threadIdx.x + 256*r;
        out[h] = (z[r]-m)*rstd*gs[h] + gb[h];
    }
}

// ===================== residual + LN (in place into X) =====================
__global__ __launch_bounds__(256) void residual_ln_kernel(
    float* __restrict__ X, const float* __restrict__ Y,
    const float* __restrict__ gs, const float* __restrict__ gb)
{
    __shared__ float red[256];
    int bs = blockIdx.x;
    float* xrow = X + (size_t)bs * H_;
    const float* yrow = Y + (size_t)bs * H_;
    float z[3];
    #pragma unroll
    for (int r = 0; r < 3; r++) {
        int h = threadIdx.x + 256*r;
        z[r] = xrow[h] + yrow[h];
    }
    float sum = z[0] + z[1] + z[2];
    sum = block_reduce_sum256(sum, red);
    float m = sum * (1.0f / H_);
    float vs = 0.f;
    #pragma unroll
    for (int r = 0; r < 3; r++) { float d = z[r]-m; vs += d*d; }
    vs = block_reduce_sum256(vs, red) * (1.0f / H_);
    float rstd = 1.0f / sqrtf(vs + LN_EPS);
    #pragma unroll
    for (int r = 0; r < 3; r++) {
        int h = threadIdx.x + 256*r;
        xrow[h] = (z[r]-m)*rstd*gs[h] + gb[h];
    }
}

// ===================== generic fp32 GEMM: C = act(actIn(A)@W + bias [+C]) ====
__global__ __launch_bounds__(256) void gemm_kernel(
    const float* __restrict__ A, int lda,
    const float* __restrict__ W, int ldb,
    float* __restrict__ C, int ldc,
    const float* __restrict__ bias,
    int M, int N, int K, int flags)
{
    __shared__ __align__(16) float As[BK][BM+4];
    __shared__ __align__(16) float Bs[BK][BN+4];
    int tid = threadIdx.x;
    int tx = tid & 15, ty = tid >> 4;
    int m0 = blockIdx.x * BM;
    int n0 = blockIdx.y * BN;
    float acc[4][4] = {};
    for (int k0 = 0; k0 < K; k0 += BK) {
        // A tile 64x16 -> As[kk][m]
        #pragma unroll
        for (int r = 0; r < 4; r++) {
            int li = tid + 256*r;
            int m  = li >> 4;
            int kk = li & 15;
            int gm = m0 + m, gk = k0 + kk;
            float v = (gm < M && gk < K) ? A[(size_t)gm*lda + gk] : 0.f;
            if (flags & GF_RELU_IN) v = fmaxf(v, 0.f);
            As[kk][m] = v;
        }
        // B tile 16x64 -> Bs[kk][n]
        #pragma unroll
        for (int r = 0; r < 4; r++) {
            int li = tid + 256*r;
            int kk = li >> 6;
            int n  = li & 63;
            int gk = k0 + kk, gn = n0 + n;
            Bs[kk][n] = (gk < K && gn < N) ? W[(size_t)gk*ldb + gn] : 0.f;
        }
        __syncthreads();
        #pragma unroll
        for (int kk = 0; kk < BK; kk++) {
            float4 a  = *(const float4*)&As[kk][ty*4];
            float4 bb = *(const float4*)&Bs[kk][tx*4];
            float av[4] = {a.x, a.y, a.z, a.w};
            float bv[4] = {bb.x, bb.y, bb.z, bb.w};
            #pragma unroll
            for (int i = 0; i < 4; i++)
                #pragma unroll
                for (int j = 0; j < 4; j++)
                    acc[i][j] += av[i] * bv[j];
        }
        __syncthreads();
    }
    #pragma unroll
    for (int i = 0; i < 4; i++) {
        int gm = m0 + ty*4 + i;
        if (gm >= M) continue;
        #pragma unroll
        for (int j = 0; j < 4; j++) {
            int gn = n0 + tx*4 + j;
            if (gn >= N) continue;
            float v = acc[i][j];
            if (bias) v += bias[gn];
            if (flags & GF_ACCUM) v += C[(size_t)gm*ldc + gn];
            if (flags & GF_RELU_OUT) v = fmaxf(v, 0.f);
            if (flags & GF_GELU_OUT) v = 0.5f*v*(1.0f + erff(v*0.70710678118654752f));
            C[(size_t)gm*ldc + gn] = v;
        }
    }
}

// ===================== attention (per (b,h) block, q loop) =====================
__global__ __launch_bounds__(128) void attn_kernel(
    const float* __restrict__ Q, const float* __restrict__ K,
    const float* __restrict__ V, const int* __restrict__ amask,
    float* __restrict__ C)
{
    int bh = blockIdx.x;
    int b = bh / NH_, h = bh % NH_;
    int tid = threadIdx.x;          // key index (blockDim=128=S_)
    __shared__ float qv[DH_];
    __shared__ float p[S_];
    __shared__ float red[128];
    size_t base = ((size_t)b * S_) * H_ + (size_t)h * DH_;
    float negt = (amask[b*S_ + tid] > 0) ? 0.f : -1e9f;
    const float* krow = K + base + (size_t)tid * H_;
    for (int q = 0; q < S_; q++) {
        if (tid < DH_) qv[tid] = Q[base + (size_t)q*H_ + tid];
        __syncthreads();
        float sc = 0.f;
        #pragma unroll
        for (int d = 0; d < DH_; d++) sc += qv[d] * krow[d];
        sc = sc * INV_SQRT_DH + negt;
        red[tid] = sc; __syncthreads();
        for (int off = 64; off > 0; off >>= 1) {
            if (tid < off) red[tid] = fmaxf(red[tid], red[tid+off]);
            __syncthreads();
        }
        float mx = red[0]; __syncthreads();
        float e = expf(sc - mx);
        p[tid] = e; red[tid] = e; __syncthreads();
        for (int off = 64; off > 0; off >>= 1) {
            if (tid < off) red[tid] += red[tid+off];
            __syncthreads();
        }
        float sm = red[0]; __syncthreads();
        if (tid < DH_) {
            float accv = 0.f;
            for (int k = 0; k < S_; k++) accv += p[k] * V[base + (size_t)k*H_ + tid];
            C[base + (size_t)q*H_ + tid] = accv / sm;
        }
        __syncthreads();
    }
}

// ===================== intent head =====================
__global__ __launch_bounds__(64) void intent_kernel(
    const float* __restrict__ X, const float* __restrict__ iW1,
    const float* __restrict__ ib1, const float* __restrict__ iW2,
    const float* __restrict__ ib2, const int* __restrict__ tgt,
    float* __restrict__ iloss, float* __restrict__ outf)
{
    int b = blockIdx.x; int j = threadIdx.x;
    __shared__ float h1[64];
    __shared__ float lg[32];
    const float* x0 = X + (size_t)b*S_*H_;
    float acc = ib1[j];
    for (int h = 0; h < H_; h++) acc += fmaxf(x0[h], 0.f) * iW1[(size_t)h*64 + j];
    h1[j] = fmaxf(acc, 0.f);
    __syncthreads();
    if (j < INTENT_) {
        float l = ib2[j];
        for (int k = 0; k < 64; k++) l += h1[k]*iW2[k*INTENT_ + j];
        lg[j] = l;
    }
    __syncthreads();
    if (j == 0) {
        float mx = -INFINITY; int bi = 0;
        for (int c = 0; c < INTENT_; c++) if (lg[c] > mx) { mx = lg[c]; bi = c; }
        float sm = 0.f;
        for (int c = 0; c < INTENT_; c++) sm += expf(lg[c]-mx);
        float lse = mx + logf(sm);
        iloss[b] = lse - lg[tgt[b]];
        outf[1 + (size_t)NT_ + b] = (float)bi;
    }
}

// ===================== CRF log-likelihood (per batch) =====================
__global__ __launch_bounds__(128) void crf_llh_kernel(
    const float* __restrict__ E_, const int* __restrict__ tags,
    const int* __restrict__ mask, const float* __restrict__ start,
    const float* __restrict__ endv, const float* __restrict__ trans,
    float* __restrict__ crfv)
{
    int b = blockIdx.x; int j = threadIdx.x;
    __shared__ float alpha[TAGS_];
    const float* E = E_ + (size_t)b*S_*TAGS_;
    if (j < TAGS_) alpha[j] = start[j] + E[j];
    __syncthreads();
    for (int t = 1; t < S_; t++) {
        int m_t = mask[b*S_ + t];
        float nv = 0.f;
        if (j < TAGS_) {
            float mx = -INFINITY;
            for (int i = 0; i < TAGS_; i++) mx = fmaxf(mx, alpha[i] + trans[i*TAGS_ + j]);
            float sm = 0.f;
            for (int i = 0; i < TAGS_; i++) sm += expf(alpha[i] + trans[i*TAGS_ + j] - mx);
            nv = mx + logf(sm) + E[t*TAGS_ + j];
        }
        __syncthreads();
        if (j < TAGS_ && m_t) alpha[j] = nv;
        __syncthreads();
    }
    if (j == 0) {
        int tag0 = tags[b*S_];
        float num = start[tag0] + E[tag0];
        int prev = tag0;
        int lsum = (mask[b*S_] ? 1 : 0);
        for (int t = 1; t < S_; t++) {
            int tg = tags[b*S_ + t];
            if (mask[b*S_ + t]) { num += trans[prev*TAGS_ + tg] + E[t*TAGS_ + tg]; lsum++; }
            prev = tg;
        }
        int last_tag = tags[b*S_ + (lsum - 1)];
        num += endv[last_tag];
        float mx = -INFINITY;
        for (int i = 0; i < TAGS_; i++) mx = fmaxf(mx, alpha[i] + endv[i]);
        float sm = 0.f;
        for (int i = 0; i < TAGS_; i++) sm += expf(alpha[i] + endv[i] - mx);
        float denom = mx + logf(sm);
        crfv[b] = num - denom;
    }
}

// ===================== Viterbi decode (per batch) =====================
__global__ __launch_bounds__(128) void viterbi_kernel(
    const float* __restrict__ E_, const int* __restrict__ mask,
    const float* __restrict__ start, const float* __restrict__ endv,
    const float* __restrict__ trans, int* __restrict__ BP,
    float* __restrict__ outf)
{
    int b = blockIdx.x; int j = threadIdx.x;
    __shared__ float alpha[TAGS_];
    const float* E = E_ + (size_t)b*S_*TAGS_;
    if (j < TAGS_) alpha[j] = start[j] + E[j];
    __syncthreads();
    for (int t = 1; t < S_; t++) {
        int m_t = mask[b*S_ + t];
        float nv = 0.f; int nb = 0;
        if (j < TAGS_) {
            float best = -INFINITY; int bi = 0;
            for (int i = 0; i < TAGS_; i++) {
                float v = alpha[i] + trans[i*TAGS_ + j];
                if (v > best) { best = v; bi = i; }   // first-max tie-break
            }
            if (m_t) { nv = best + E[t*TAGS_ + j]; nb = bi; }
            else     { nv = alpha[j];               nb = j;  }
        }
        __syncthreads();
        if (j < TAGS_) {
            alpha[j] = nv;
            BP[((size_t)b*(S_-1) + (t-1))*TAGS_ + j] = nb;
        }
        __syncthreads();
    }
    if (j == 0) {
        float best = -INFINITY; int bi = 0;
        for (int i = 0; i < TAGS_; i++) {
            float v = alpha[i] + endv[i];
            if (v > best) { best = v; bi = i; }
        }
        int tag = bi;
        outf[1 + (size_t)b*S_ + (S_-1)] = (float)tag;
        for (int t = S_-1; t >= 1; t--) {
            tag = BP[((size_t)b*(S_-1) + (t-1))*TAGS_ + tag];
            outf[1 + (size_t)b*S_ + (t-1)] = (float)tag;
        }
    }
}

// ===================== final joint loss =====================
__global__ void combine_kernel(const float* __restrict__ iloss,
                               const float* __restrict__ crfv,
                               const float* __restrict__ lv,
                               float* __restrict__ outf)
{
    if (threadIdx.x == 0 && blockIdx.x == 0) {
        float si = 0.f, sc = 0.f;
        for (int b = 0; b < B_; b++) { si += iloss[b]; sc += crfv[b]; }
        float p1 = expf(-lv[0]), p2 = expf(-lv[1]);
        float slots_loss = -sc;
        outf[0] = p1*si + (float)B_*lv[0] + p2*slots_loss + lv[1];
    }
}

// ===================== host launch =====================
extern "C" void kernel_launch(void* const* d_in, const int* in_sizes, int n_in,
                              void* d_out, int out_size, void* d_ws, size_t ws_size,
                              hipStream_t stream) {
    const int*   ids   = (const int*)  d_in[0];
    const int*   amask = (const int*)  d_in[1];
    const int*   itgt  = (const int*)  d_in[2];
    const int*   stgt  = (const int*)  d_in[3];
    const int*   smask = (const int*)  d_in[4];
    const float* we    = (const float*)d_in[5];
    const float* pe    = (const float*)d_in[6];
    const float* embs  = (const float*)d_in[7];
    const float* embb  = (const float*)d_in[8];
    const float* Wq    = (const float*)d_in[9];
    const float* bq    = (const float*)d_in[10];
    const float* Wk    = (const float*)d_in[11];
    const float* bk    = (const float*)d_in[12];
    const float* Wv    = (const float*)d_in[13];
    const float* bv    = (const float*)d_in[14];
    const float* Wo    = (const float*)d_in[15];
    const float* bo    = (const float*)d_in[16];
    const float* sas   = (const float*)d_in[17];
    const float* sab   = (const float*)d_in[18];
    const float* W1f   = (const float*)d_in[19];
    const float* b1f   = (const float*)d_in[20];
    const float* W2f   = (const float*)d_in[21];
    const float* b2f   = (const float*)d_in[22];
    const float* ols   = (const float*)d_in[23];
    const float* olb   = (const float*)d_in[24];
    const float* iW1   = (const float*)d_in[25];
    const float* ib1   = (const float*)d_in[26];
    const float* iW2   = (const float*)d_in[27];
    const float* ib2   = (const float*)d_in[28];
    const float* sW1   = (const float*)d_in[29];
    const float* sb1   = (const float*)d_in[30];
    const float* sW2   = (const float*)d_in[31];
    const float* sb2   = (const float*)d_in[32];
    const float* crfs  = (const float*)d_in[33];
    const float* crfe  = (const float*)d_in[34];
    const float* crft  = (const float*)d_in[35];
    const float* lv    = (const float*)d_in[36];

    float* outf = (float*)d_out;
    float* ws = (float*)d_ws;
    const size_t NB = (size_t)NT_ * H_;          // 6,291,456 floats
    float* X  = ws;
    float* Qb = ws + 1*NB;
    float* Kb = ws + 2*NB;                        // F-half spans Kb..Vb (2*NB)
    float* Vb = ws + 3*NB;
    float* Cb = ws + 4*NB;
    float* iloss = ws + 5*NB;                     // 64 floats
    float* crfv  = ws + 5*NB + 64;                // 64 floats

    auto gemm = [&](const float* A, int lda, const float* W, int ldb,
                    float* C, int ldc, const float* bias,
                    int M, int N, int K, int flags) {
        dim3 g((M+BM-1)/BM, (N+BN-1)/BN);
        hipLaunchKernelGGL(gemm_kernel, g, dim3(256), 0, stream,
                           A, lda, W, ldb, C, ldc, bias, M, N, K, flags);
    };

    // embedding + LN
    hipLaunchKernelGGL(embed_ln_kernel, dim3(NT_), dim3(256), 0, stream,
                       ids, we, pe, embs, embb, X);

    for (int i = 0; i < L_; i++) {
        const size_t WO = (size_t)i*H_*H_;
        // Q,K,V projections
        gemm(X, H_, Wq + WO, H_, Qb, H_, bq + i*H_, NT_, H_, H_, 0);
        gemm(X, H_, Wk + WO, H_, Kb, H_, bk + i*H_, NT_, H_, H_, 0);
        gemm(X, H_, Wv + WO, H_, Vb, H_, bv + i*H_, NT_, H_, H_, 0);
        // attention -> Cb
        hipLaunchKernelGGL(attn_kernel, dim3(B_*NH_), dim3(128), 0, stream,
                           Qb, Kb, Vb, amask, Cb);
        // output projection -> Qb (AO)
        gemm(Cb, H_, Wo + WO, H_, Qb, H_, bo + i*H_, NT_, H_, H_, 0);
        // x = LN(x + AO)
        hipLaunchKernelGGL(residual_ln_kernel, dim3(NT_), dim3(256), 0, stream,
                           X, Qb, sas + i*H_, sab + i*H_);
        // FF in two 1536-column chunks; F-half lives in Kb..Vb (2*NB floats)
        float* Fh = Kb;
        for (int c = 0; c < 2; c++) {
            const int CW = FF_/2;                 // 1536
            gemm(X, H_, W1f + (size_t)i*H_*FF_ + c*CW, FF_,
                 Fh, CW, b1f + (size_t)i*FF_ + c*CW,
                 NT_, CW, H_, GF_GELU_OUT);
            gemm(Fh, CW, W2f + (size_t)i*FF_*H_ + (size_t)c*CW*H_, H_,
                 Cb, H_, (c == 0) ? (b2f + i*H_) : nullptr,
                 NT_, H_, CW, (c == 0) ? 0 : GF_ACCUM);
        }
        // x = LN(x + FF)
        hipLaunchKernelGGL(residual_ln_kernel, dim3(NT_), dim3(256), 0, stream,
                           X, Cb, ols + i*H_, olb + i*H_);
    }

    // intent head
    hipLaunchKernelGGL(intent_kernel, dim3(B_), dim3(64), 0, stream,
                       X, iW1, ib1, iW2, ib2, itgt, iloss, outf);

    // slots head: H1 = relu(relu(X)@sW1 + sb1) -> Qb ; logits -> Cb
    gemm(X, H_, sW1, 256, Qb, 256, sb1, NT_, 256, H_, GF_RELU_IN | GF_RELU_OUT);
    gemm(Qb, 256, sW2, TAGS_, Cb, TAGS_, sb2, NT_, TAGS_, 256, 0);

    // CRF log-likelihood + Viterbi
    hipLaunchKernelGGL(crf_llh_kernel, dim3(B_), dim3(128), 0, stream,
                       Cb, stgt, smask, crfs, crfe, crft, crfv);
    hipLaunchKernelGGL(viterbi_kernel, dim3(B_), dim3(128), 0, stream,
                       Cb, smask, crfs, crfe, crft, (int*)Vb, outf);

    // joint loss
    hipLaunchKernelGGL(combine_kernel, dim3(1), dim3(64), 0, stream,
                       iloss, crfv, lv, outf);
}

// Round 2
// 13702.998 us; speedup vs baseline: 1.9736x; 1.9736x over previous
//
#include <hip/hip_runtime.h>
#include <math.h>

// ---- problem constants ----
#define B_      64
#define S_      128
#define H_      768
#define L_      6
#define NH_     12
#define DH_     64
#define FF_     3072
#define INTENT_ 22
#define TAGS_   122
#define NT_     (B_*S_)          // 8192 tokens
#define LN_EPS  1e-12f
#define INV_SQRT_DH 0.125f       // 1/sqrt(64)

#define GF_RELU_IN  1
#define GF_RELU_OUT 2
#define GF_GELU_OUT 4
#define GF_ACCUM    8

typedef _Float16 half8 __attribute__((ext_vector_type(8)));
typedef float    f32x4 __attribute__((ext_vector_type(4)));

// ===================== block reduction helper (256 thr) =====================
__device__ inline float block_reduce_sum256(float v, float* red) {
    int tid = threadIdx.x;
    red[tid] = v; __syncthreads();
    for (int off = 128; off > 0; off >>= 1) {
        if (tid < off) red[tid] += red[tid + off];
        __syncthreads();
    }
    float r = red[0]; __syncthreads();
    return r;
}

// ===================== embedding + LN =====================
__global__ __launch_bounds__(256) void embed_ln_kernel(
    const int* __restrict__ ids, const float* __restrict__ we,
    const float* __restrict__ pe, const float* __restrict__ gs,
    const float* __restrict__ gb, float* __restrict__ X)
{
    __shared__ float red[256];
    int bs = blockIdx.x;
    int sq = bs % S_;
    int id = ids[bs];
    const float* wrow = we + (size_t)id * H_;
    const float* prow = pe + (size_t)sq * H_;
    float z[3];
    #pragma unroll
    for (int r = 0; r < 3; r++) {
        int h = threadIdx.x + 256*r;
        z[r] = wrow[h] + prow[h];
    }
    float sum = z[0] + z[1] + z[2];
    sum = block_reduce_sum256(sum, red);
    float m = sum * (1.0f / H_);
    float vs = 0.f;
    #pragma unroll
    for (int r = 0; r < 3; r++) { float d = z[r]-m; vs += d*d; }
    vs = block_reduce_sum256(vs, red) * (1.0f / H_);
    float rstd = 1.0f / sqrtf(vs + LN_EPS);
    float* out = X + (size_t)bs * H_;
    #pragma unroll
    for (int r = 0; r < 3; r++) {
        int h = threadIdx.x + 256*r;
        out[h] = (z[r]-m)*rstd*gs[h] + gb[h];
    }
}

// ===================== residual + LN (in place into X) =====================
__global__ __launch_bounds__(256) void residual_ln_kernel(
    float* __restrict__ X, const float* __restrict__ Y,
    const float* __restrict__ gs, const float* __restrict__ gb)
{
    __shared__ float red[256];
    int bs = blockIdx.x;
    float* xrow = X + (size_t)bs * H_;
    const float* yrow = Y + (size_t)bs * H_;
    float z[3];
    #pragma unroll
    for (int r = 0; r < 3; r++) {
        int h = threadIdx.x + 256*r;
        z[r] = xrow[h] + yrow[h];
    }
    float sum = z[0] + z[1] + z[2];
    sum = block_reduce_sum256(sum, red);
    float m = sum * (1.0f / H_);
    float vs = 0.f;
    #pragma unroll
    for (int r = 0; r < 3; r++) { float d = z[r]-m; vs += d*d; }
    vs = block_reduce_sum256(vs, red) * (1.0f / H_);
    float rstd = 1.0f / sqrtf(vs + LN_EPS);
    #pragma unroll
    for (int r = 0; r < 3; r++) {
        int h = threadIdx.x + 256*r;
        xrow[h] = (z[r]-m)*rstd*gs[h] + gb[h];
    }
}

// ===================== MFMA fp16-split GEMM =====================
// C[MxN] = act(A[MxK] @ W[KxN] + bias [+C]) via fp16 hi/lo split (3 MFMAs).
// Requires M%128==0, N%128==0, K%32==0.
#define ASTR 40   // halves per LDS row (32 + 8 pad)
__global__ __launch_bounds__(256) void gemm_mfma_kernel(
    const float* __restrict__ A, int lda,
    const float* __restrict__ W, int ldb,
    float* __restrict__ C, int ldc,
    const float* __restrict__ bias,
    int M, int N, int K, int flags)
{
    __shared__ _Float16 Ah[128*ASTR], Al[128*ASTR], Bh[128*ASTR], Bl[128*ASTR];
    const int tid  = threadIdx.x;
    const int lane = tid & 63;
    const int wid  = tid >> 6;
    const int wm   = wid & 1, wn = wid >> 1;
    const int m0   = blockIdx.x * 128, n0 = blockIdx.y * 128;
    const int l15  = lane & 15, quad = lane >> 4;

    f32x4 acc[4][4];
    #pragma unroll
    for (int i = 0; i < 4; i++)
        #pragma unroll
        for (int j = 0; j < 4; j++)
            acc[i][j] = (f32x4){0.f,0.f,0.f,0.f};

    const int ar = tid >> 3;        // A row 0..31 (+32*r)
    const int ac = (tid & 7) * 4;   // A col 0,4..28
    const int bk = tid >> 5;        // B k 0..7 (+8*r)
    const int bc = (tid & 31) * 4;  // B col 0,4..124

    for (int k0 = 0; k0 < K; k0 += 32) {
        // ---- stage A: 128x32 -> Ah/Al[m][k], row-major stride ASTR ----
        #pragma unroll
        for (int r = 0; r < 4; r++) {
            int m = ar + r*32;
            float4 v = *(const float4*)&A[(size_t)(m0+m)*lda + k0 + ac];
            if (flags & GF_RELU_IN) {
                v.x = fmaxf(v.x,0.f); v.y = fmaxf(v.y,0.f);
                v.z = fmaxf(v.z,0.f); v.w = fmaxf(v.w,0.f);
            }
            union { _Float16 h[4]; uint2 u; } ph, pl;
            ph.h[0]=(_Float16)v.x; ph.h[1]=(_Float16)v.y;
            ph.h[2]=(_Float16)v.z; ph.h[3]=(_Float16)v.w;
            pl.h[0]=(_Float16)(v.x-(float)ph.h[0]);
            pl.h[1]=(_Float16)(v.y-(float)ph.h[1]);
            pl.h[2]=(_Float16)(v.z-(float)ph.h[2]);
            pl.h[3]=(_Float16)(v.w-(float)ph.h[3]);
            *(uint2*)&Ah[m*ASTR + ac] = ph.u;
            *(uint2*)&Al[m*ASTR + ac] = pl.u;
        }
        // ---- stage B: 32x128 transposed -> Bh/Bl[n][k] ----
        #pragma unroll
        for (int r = 0; r < 4; r++) {
            int k = bk + r*8;
            const float4 v = *(const float4*)&W[(size_t)(k0+k)*ldb + n0 + bc];
            float vv[4] = {v.x, v.y, v.z, v.w};
            #pragma unroll
            for (int e = 0; e < 4; e++) {
                _Float16 h = (_Float16)vv[e];
                _Float16 l = (_Float16)(vv[e] - (float)h);
                Bh[(bc+e)*ASTR + k] = h;
                Bl[(bc+e)*ASTR + k] = l;
            }
        }
        __syncthreads();
        // ---- fragments + MFMA ----
        half8 afh[4], afl[4], bfh[4], bfl[4];
        #pragma unroll
        for (int i = 0; i < 4; i++) {
            int m = wm*64 + i*16 + l15;
            afh[i] = *(const half8*)&Ah[m*ASTR + quad*8];
            afl[i] = *(const half8*)&Al[m*ASTR + quad*8];
            int n = wn*64 + i*16 + l15;
            bfh[i] = *(const half8*)&Bh[n*ASTR + quad*8];
            bfl[i] = *(const half8*)&Bl[n*ASTR + quad*8];
        }
        #pragma unroll
        for (int i = 0; i < 4; i++)
            #pragma unroll
            for (int j = 0; j < 4; j++) {
                acc[i][j] = __builtin_amdgcn_mfma_f32_16x16x32_f16(afh[i], bfh[j], acc[i][j], 0,0,0);
                acc[i][j] = __builtin_amdgcn_mfma_f32_16x16x32_f16(afh[i], bfl[j], acc[i][j], 0,0,0);
                acc[i][j] = __builtin_amdgcn_mfma_f32_16x16x32_f16(afl[i], bfh[j], acc[i][j], 0,0,0);
            }
        __syncthreads();
    }
    // ---- epilogue: C/D layout col=lane&15, row=quad*4+reg ----
    #pragma unroll
    for (int i = 0; i < 4; i++)
        #pragma unroll
        for (int j = 0; j < 4; j++)
            #pragma unroll
            for (int r = 0; r < 4; r++) {
                int gm = m0 + wm*64 + i*16 + quad*4 + r;
                int gn = n0 + wn*64 + j*16 + l15;
                float v = acc[i][j][r];
                if (bias) v += bias[gn];
                if (flags & GF_ACCUM) v += C[(size_t)gm*ldc + gn];
                if (flags & GF_RELU_OUT) v = fmaxf(v, 0.f);
                if (flags & GF_GELU_OUT) v = 0.5f*v*(1.0f + erff(v*0.70710678118654752f));
                C[(size_t)gm*ldc + gn] = v;
            }
}

// ===================== fp32 GEMM (kept for small head GEMMs) =====================
#define BM 64
#define BN 64
#define BK 16
__global__ __launch_bounds__(256) void gemm_kernel(
    const float* __restrict__ A, int lda,
    const float* __restrict__ W, int ldb,
    float* __restrict__ C, int ldc,
    const float* __restrict__ bias,
    int M, int N, int K, int flags)
{
    __shared__ __align__(16) float As[BK][BM+4];
    __shared__ __align__(16) float Bs[BK][BN+4];
    int tid = threadIdx.x;
    int tx = tid & 15, ty = tid >> 4;
    int m0 = blockIdx.x * BM;
    int n0 = blockIdx.y * BN;
    float acc[4][4] = {};
    for (int k0 = 0; k0 < K; k0 += BK) {
        #pragma unroll
        for (int r = 0; r < 4; r++) {
            int li = tid + 256*r;
            int m  = li >> 4;
            int kk = li & 15;
            int gm = m0 + m, gk = k0 + kk;
            float v = (gm < M && gk < K) ? A[(size_t)gm*lda + gk] : 0.f;
            if (flags & GF_RELU_IN) v = fmaxf(v, 0.f);
            As[kk][m] = v;
        }
        #pragma unroll
        for (int r = 0; r < 4; r++) {
            int li = tid + 256*r;
            int kk = li >> 6;
            int n  = li & 63;
            int gk = k0 + kk, gn = n0 + n;
            Bs[kk][n] = (gk < K && gn < N) ? W[(size_t)gk*ldb + gn] : 0.f;
        }
        __syncthreads();
        #pragma unroll
        for (int kk = 0; kk < BK; kk++) {
            float4 a  = *(const float4*)&As[kk][ty*4];
            float4 bb = *(const float4*)&Bs[kk][tx*4];
            float av[4] = {a.x, a.y, a.z, a.w};
            float bv[4] = {bb.x, bb.y, bb.z, bb.w};
            #pragma unroll
            for (int i = 0; i < 4; i++)
                #pragma unroll
                for (int j = 0; j < 4; j++)
                    acc[i][j] += av[i] * bv[j];
        }
        __syncthreads();
    }
    #pragma unroll
    for (int i = 0; i < 4; i++) {
        int gm = m0 + ty*4 + i;
        if (gm >= M) continue;
        #pragma unroll
        for (int j = 0; j < 4; j++) {
            int gn = n0 + tx*4 + j;
            if (gn >= N) continue;
            float v = acc[i][j];
            if (bias) v += bias[gn];
            if (flags & GF_ACCUM) v += C[(size_t)gm*ldc + gn];
            if (flags & GF_RELU_OUT) v = fmaxf(v, 0.f);
            if (flags & GF_GELU_OUT) v = 0.5f*v*(1.0f + erff(v*0.70710678118654752f));
            C[(size_t)gm*ldc + gn] = v;
        }
    }
}

// ===================== attention (per (b,h) block, q loop) =====================
__global__ __launch_bounds__(128) void attn_kernel(
    const float* __restrict__ Q, const float* __restrict__ K,
    const float* __restrict__ V, const int* __restrict__ amask,
    float* __restrict__ C)
{
    int bh = blockIdx.x;
    int b = bh / NH_, h = bh % NH_;
    int tid = threadIdx.x;
    __shared__ float qv[DH_];
    __shared__ float p[S_];
    __shared__ float red[128];
    size_t base = ((size_t)b * S_) * H_ + (size_t)h * DH_;
    float negt = (amask[b*S_ + tid] > 0) ? 0.f : -1e9f;
    const float* krow = K + base + (size_t)tid * H_;
    for (int q = 0; q < S_; q++) {
        if (tid < DH_) qv[tid] = Q[base + (size_t)q*H_ + tid];
        __syncthreads();
        float sc = 0.f;
        #pragma unroll
        for (int d = 0; d < DH_; d++) sc += qv[d] * krow[d];
        sc = sc * INV_SQRT_DH + negt;
        red[tid] = sc; __syncthreads();
        for (int off = 64; off > 0; off >>= 1) {
            if (tid < off) red[tid] = fmaxf(red[tid], red[tid+off]);
            __syncthreads();
        }
        float mx = red[0]; __syncthreads();
        float e = expf(sc - mx);
        p[tid] = e; red[tid] = e; __syncthreads();
        for (int off = 64; off > 0; off >>= 1) {
            if (tid < off) red[tid] += red[tid+off];
            __syncthreads();
        }
        float sm = red[0]; __syncthreads();
        if (tid < DH_) {
            float accv = 0.f;
            for (int k = 0; k < S_; k++) accv += p[k] * V[base + (size_t)k*H_ + tid];
            C[base + (size_t)q*H_ + tid] = accv / sm;
        }
        __syncthreads();
    }
}

// ===================== intent head =====================
__global__ __launch_bounds__(64) void intent_kernel(
    const float* __restrict__ X, const float* __restrict__ iW1,
    const float* __restrict__ ib1, const float* __restrict__ iW2,
    const float* __restrict__ ib2, const int* __restrict__ tgt,
    float* __restrict__ iloss, float* __restrict__ outf)
{
    int b = blockIdx.x; int j = threadIdx.x;
    __shared__ float h1[64];
    __shared__ float lg[32];
    const float* x0 = X + (size_t)b*S_*H_;
    float acc = ib1[j];
    for (int h = 0; h < H_; h++) acc += fmaxf(x0[h], 0.f) * iW1[(size_t)h*64 + j];
    h1[j] = fmaxf(acc, 0.f);
    __syncthreads();
    if (j < INTENT_) {
        float l = ib2[j];
        for (int k = 0; k < 64; k++) l += h1[k]*iW2[k*INTENT_ + j];
        lg[j] = l;
    }
    __syncthreads();
    if (j == 0) {
        float mx = -INFINITY; int bi = 0;
        for (int c = 0; c < INTENT_; c++) if (lg[c] > mx) { mx = lg[c]; bi = c; }
        float sm = 0.f;
        for (int c = 0; c < INTENT_; c++) sm += expf(lg[c]-mx);
        float lse = mx + logf(sm);
        iloss[b] = lse - lg[tgt[b]];
        outf[1 + (size_t)NT_ + b] = (float)bi;
    }
}

// ===================== CRF log-likelihood (per batch) =====================
// logsumexp_i(alpha_i + T_ij) = mx + log( sum_i e^{alpha_i-mx} * e^{T_ij} )
#define TSTR 124
__global__ __launch_bounds__(128) void crf_llh_kernel(
    const float* __restrict__ E_, const int* __restrict__ tags,
    const int* __restrict__ mask, const float* __restrict__ start,
    const float* __restrict__ endv, const float* __restrict__ trans,
    float* __restrict__ crfv)
{
    int b = blockIdx.x; int j = threadIdx.x;
    __shared__ __align__(16) float etT[TAGS_*TSTR];   // etT[j*TSTR+i] = exp(trans[i][j])
    __shared__ __align__(16) float alpha[TAGS_];
    __shared__ __align__(16) float ealpha[TAGS_];
    __shared__ __align__(16) float red[128];
    const float* E = E_ + (size_t)b*S_*TAGS_;
    for (int i = 0; i < TAGS_; i++)
        if (j < TAGS_) etT[(size_t)j*TSTR + i] = expf(trans[i*TAGS_ + j]);
    if (j < TAGS_) alpha[j] = start[j] + E[j];
    __syncthreads();

    for (int t = 1; t < S_; t++) {
        float av = (j < TAGS_) ? alpha[j] : -1e30f;
        red[j] = av; __syncthreads();
        for (int off = 64; off > 0; off >>= 1) {
            if (j < off) red[j] = fmaxf(red[j], red[j+off]);
            __syncthreads();
        }
        float mx = red[0];
        if (j < TAGS_) ealpha[j] = expf(av - mx);
        __syncthreads();
        float nv = 0.f;
        int m_t = mask[b*S_ + t];
        if (j < TAGS_) {
            const float* tr = &etT[(size_t)j*TSTR];
            float s = 0.f;
            #pragma unroll 5
            for (int i = 0; i < 120; i += 4) {
                float4 ea = *(const float4*)&ealpha[i];
                float4 tt = *(const float4*)&tr[i];
                s += ea.x*tt.x + ea.y*tt.y + ea.z*tt.z + ea.w*tt.w;
            }
            s += ealpha[120]*tr[120] + ealpha[121]*tr[121];
            nv = mx + logf(s) + E[t*TAGS_ + j];
        }
        __syncthreads();
        if (j < TAGS_ && m_t) alpha[j] = nv;
        __syncthreads();
    }

    // numerator: parallel over timesteps
    int tg  = (j < S_) ? tags[b*S_ + j] : 0;
    int mk  = (j < S_) ? mask[b*S_ + j] : 0;
    int tgp = (j >= 1 && j < S_) ? tags[b*S_ + j - 1] : 0;
    float term = 0.f;
    if (j >= 1 && j < S_ && mk)
        term = trans[tgp*TAGS_ + tg] + E[(size_t)j*TAGS_ + tg];
    red[j] = term; __syncthreads();
    for (int off = 64; off > 0; off >>= 1) {
        if (j < off) red[j] += red[j+off];
        __syncthreads();
    }
    float numsum = red[0]; __syncthreads();
    red[j] = (float)mk; __syncthreads();
    for (int off = 64; off > 0; off >>= 1) {
        if (j < off) red[j] += red[j+off];
        __syncthreads();
    }
    int msum = (int)red[0]; __syncthreads();
    // denominator logsumexp(alpha + end)
    float dv = (j < TAGS_) ? alpha[j] + endv[j] : -1e30f;
    red[j] = dv; __syncthreads();
    for (int off = 64; off > 0; off >>= 1) {
        if (j < off) red[j] = fmaxf(red[j], red[j+off]);
        __syncthreads();
    }
    float dmx = red[0]; __syncthreads();
    red[j] = (j < TAGS_) ? expf(dv - dmx) : 0.f;
    __syncthreads();
    for (int off = 64; off > 0; off >>= 1) {
        if (j < off) red[j] += red[j+off];
        __syncthreads();
    }
    if (j == 0) {
        float denom = dmx + logf(red[0]);
        int tag0 = tags[b*S_];
        int last_tag = tags[b*S_ + (msum - 1)];
        float num = start[tag0] + E[tag0] + numsum + endv[last_tag];
        crfv[b] = num - denom;
    }
}

// ===================== Viterbi decode (per batch) =====================
__global__ __launch_bounds__(128) void viterbi_kernel(
    const float* __restrict__ E_, const int* __restrict__ mask,
    const float* __restrict__ start, const float* __restrict__ endv,
    const float* __restrict__ trans, int* __restrict__ BP,
    float* __restrict__ outf)
{
    int b = blockIdx.x; int j = threadIdx.x;
    __shared__ __align__(16) float tT[TAGS_*TSTR];   // tT[j*TSTR+i] = trans[i][j]
    __shared__ __align__(16) float alpha[TAGS_];
    const float* E = E_ + (size_t)b*S_*TAGS_;
    for (int i = 0; i < TAGS_; i++)
        if (j < TAGS_) tT[(size_t)j*TSTR + i] = trans[i*TAGS_ + j];
    if (j < TAGS_) alpha[j] = start[j] + E[j];
    __syncthreads();
    for (int t = 1; t < S_; t++) {
        int m_t = mask[b*S_ + t];
        float nv = 0.f; int nb = 0;
        if (j < TAGS_) {
            const float* tr = &tT[(size_t)j*TSTR];
            float best = -1e30f; int bi = 0;
            #pragma unroll 5
            for (int i = 0; i < 120; i += 4) {
                float4 al = *(const float4*)&alpha[i];
                float4 tt = *(const float4*)&tr[i];
                float v0 = al.x + tt.x; if (v0 > best) { best = v0; bi = i;   }
                float v1 = al.y + tt.y; if (v1 > best) { best = v1; bi = i+1; }
                float v2 = al.z + tt.z; if (v2 > best) { best = v2; bi = i+2; }
                float v3 = al.w + tt.w; if (v3 > best) { best = v3; bi = i+3; }
            }
            { float v = alpha[120] + tr[120]; if (v > best) { best = v; bi = 120; } }
            { float v = alpha[121] + tr[121]; if (v > best) { best = v; bi = 121; } }
            if (m_t) { nv = best + E[(size_t)t*TAGS_ + j]; nb = bi; }
            else     { nv = alpha[j];                       nb = j;  }
        }
        __syncthreads();
        if (j < TAGS_) {
            alpha[j] = nv;
            BP[((size_t)b*(S_-1) + (t-1))*TAGS_ + j] = nb;
        }
        __syncthreads();
    }
    if (j == 0) {
        float best = -1e30f; int bi = 0;
        for (int i = 0; i < TAGS_; i++) {
            float v = alpha[i] + endv[i];
            if (v > best) { best = v; bi = i; }
        }
        int tag = bi;
        outf[1 + (size_t)b*S_ + (S_-1)] = (float)tag;
        for (int t = S_-1; t >= 1; t--) {
            tag = BP[((size_t)b*(S_-1) + (t-1))*TAGS_ + tag];
            outf[1 + (size_t)b*S_ + (t-1)] = (float)tag;
        }
    }
}

// ===================== final joint loss =====================
__global__ void combine_kernel(const float* __restrict__ iloss,
                               const float* __restrict__ crfv,
                               const float* __restrict__ lv,
                               float* __restrict__ outf)
{
    if (threadIdx.x == 0 && blockIdx.x == 0) {
        float si = 0.f, sc = 0.f;
        for (int b = 0; b < B_; b++) { si += iloss[b]; sc += crfv[b]; }
        float p1 = expf(-lv[0]), p2 = expf(-lv[1]);
        float slots_loss = -sc;
        outf[0] = p1*si + (float)B_*lv[0] + p2*slots_loss + lv[1];
    }
}

// ===================== host launch =====================
extern "C" void kernel_launch(void* const* d_in, const int* in_sizes, int n_in,
                              void* d_out, int out_size, void* d_ws, size_t ws_size,
                              hipStream_t stream) {
    const int*   ids   = (const int*)  d_in[0];
    const int*   amask = (const int*)  d_in[1];
    const int*   itgt  = (const int*)  d_in[2];
    const int*   stgt  = (const int*)  d_in[3];
    const int*   smask = (const int*)  d_in[4];
    const float* we    = (const float*)d_in[5];
    const float* pe    = (const float*)d_in[6];
    const float* embs  = (const float*)d_in[7];
    const float* embb  = (const float*)d_in[8];
    const float* Wq    = (const float*)d_in[9];
    const float* bq    = (const float*)d_in[10];
    const float* Wk    = (const float*)d_in[11];
    const float* bk    = (const float*)d_in[12];
    const float* Wv    = (const float*)d_in[13];
    const float* bv    = (const float*)d_in[14];
    const float* Wo    = (const float*)d_in[15];
    const float* bo    = (const float*)d_in[16];
    const float* sas   = (const float*)d_in[17];
    const float* sab   = (const float*)d_in[18];
    const float* W1f   = (const float*)d_in[19];
    const float* b1f   = (const float*)d_in[20];
    const float* W2f   = (const float*)d_in[21];
    const float* b2f   = (const float*)d_in[22];
    const float* ols   = (const float*)d_in[23];
    const float* olb   = (const float*)d_in[24];
    const float* iW1   = (const float*)d_in[25];
    const float* ib1   = (const float*)d_in[26];
    const float* iW2   = (const float*)d_in[27];
    const float* ib2   = (const float*)d_in[28];
    const float* sW1   = (const float*)d_in[29];
    const float* sb1   = (const float*)d_in[30];
    const float* sW2   = (const float*)d_in[31];
    const float* sb2   = (const float*)d_in[32];
    const float* crfs  = (const float*)d_in[33];
    const float* crfe  = (const float*)d_in[34];
    const float* crft  = (const float*)d_in[35];
    const float* lv    = (const float*)d_in[36];

    float* outf = (float*)d_out;
    float* ws = (float*)d_ws;
    const size_t NB = (size_t)NT_ * H_;
    float* X  = ws;
    float* Qb = ws + 1*NB;
    float* Kb = ws + 2*NB;
    float* Vb = ws + 3*NB;
    float* Cb = ws + 4*NB;
    float* iloss = ws + 5*NB;
    float* crfv  = ws + 5*NB + 64;

    auto gemm_f = [&](const float* A, int lda, const float* W, int ldb,
                      float* C, int ldc, const float* bias,
                      int M, int N, int K, int flags) {
        dim3 g(M/128, N/128);
        hipLaunchKernelGGL(gemm_mfma_kernel, g, dim3(256), 0, stream,
                           A, lda, W, ldb, C, ldc, bias, M, N, K, flags);
    };
    auto gemm32 = [&](const float* A, int lda, const float* W, int ldb,
                      float* C, int ldc, const float* bias,
                      int M, int N, int K, int flags) {
        dim3 g((M+BM-1)/BM, (N+BN-1)/BN);
        hipLaunchKernelGGL(gemm_kernel, g, dim3(256), 0, stream,
                           A, lda, W, ldb, C, ldc, bias, M, N, K, flags);
    };

    hipLaunchKernelGGL(embed_ln_kernel, dim3(NT_), dim3(256), 0, stream,
                       ids, we, pe, embs, embb, X);

    for (int i = 0; i < L_; i++) {
        const size_t WO = (size_t)i*H_*H_;
        gemm_f(X, H_, Wq + WO, H_, Qb, H_, bq + i*H_, NT_, H_, H_, 0);
        gemm_f(X, H_, Wk + WO, H_, Kb, H_, bk + i*H_, NT_, H_, H_, 0);
        gemm_f(X, H_, Wv + WO, H_, Vb, H_, bv + i*H_, NT_, H_, H_, 0);
        hipLaunchKernelGGL(attn_kernel, dim3(B_*NH_), dim3(128), 0, stream,
                           Qb, Kb, Vb, amask, Cb);
        gemm_f(Cb, H_, Wo + WO, H_, Qb, H_, bo + i*H_, NT_, H_, H_, 0);
        hipLaunchKernelGGL(residual_ln_kernel, dim3(NT_), dim3(256), 0, stream,
                           X, Qb, sas + i*H_, sab + i*H_);
        float* Fh = Kb;   // spans Kb..Vb (2*NB)
        for (int c = 0; c < 2; c++) {
            const int CW = FF_/2;  // 1536
            gemm_f(X, H_, W1f + (size_t)i*H_*FF_ + c*CW, FF_,
                   Fh, CW, b1f + (size_t)i*FF_ + c*CW,
                   NT_, CW, H_, GF_GELU_OUT);
            gemm_f(Fh, CW, W2f + (size_t)i*FF_*H_ + (size_t)c*CW*H_, H_,
                   Cb, H_, (c == 0) ? (b2f + i*H_) : nullptr,
                   NT_, H_, CW, (c == 0) ? 0 : GF_ACCUM);
        }
        hipLaunchKernelGGL(residual_ln_kernel, dim3(NT_), dim3(256), 0, stream,
                           X, Cb, ols + i*H_, olb + i*H_);
    }

    hipLaunchKernelGGL(intent_kernel, dim3(B_), dim3(64), 0, stream,
                       X, iW1, ib1, iW2, ib2, itgt, iloss, outf);

    // slots head
    gemm_f(X, H_, sW1, 256, Qb, 256, sb1, NT_, 256, H_, GF_RELU_IN | GF_RELU_OUT);
    gemm32(Qb, 256, sW2, TAGS_, Cb, TAGS_, sb2, NT_, TAGS_, 256, 0);

    hipLaunchKernelGGL(crf_llh_kernel, dim3(B_), dim3(128), 0, stream,
                       Cb, stgt, smask, crfs, crfe, crft, crfv);
    hipLaunchKernelGGL(viterbi_kernel, dim3(B_), dim3(128), 0, stream,
                       Cb, smask, crfs, crfe, crft, (int*)Vb, outf);

    hipLaunchKernelGGL(combine_kernel, dim3(1), dim3(64), 0, stream,
                       iloss, crfv, lv, outf);
}

// Round 3
// 4903.865 us; speedup vs baseline: 5.5148x; 2.7943x over previous
//
#include <hip/hip_runtime.h>
#include <math.h>

// ---- problem constants ----
#define B_      64
#define S_      128
#define H_      768
#define L_      6
#define NH_     12
#define DH_     64
#define FF_     3072
#define INTENT_ 22
#define TAGS_   122
#define NT_     (B_*S_)          // 8192 tokens
#define LN_EPS  1e-12f
#define INV_SQRT_DH 0.125f

#define GF_RELU_IN  1
#define GF_RELU_OUT 2
#define GF_GELU_OUT 4
#define GF_ACCUM    8

typedef _Float16 half8 __attribute__((ext_vector_type(8)));
typedef float    f32x4 __attribute__((ext_vector_type(4)));

// ===================== block reduction helper (256 thr) =====================
__device__ inline float block_reduce_sum256(float v, float* red) {
    int tid = threadIdx.x;
    red[tid] = v; __syncthreads();
    for (int off = 128; off > 0; off >>= 1) {
        if (tid < off) red[tid] += red[tid + off];
        __syncthreads();
    }
    float r = red[0]; __syncthreads();
    return r;
}

// ===================== embedding + LN =====================
__global__ __launch_bounds__(256) void embed_ln_kernel(
    const int* __restrict__ ids, const float* __restrict__ we,
    const float* __restrict__ pe, const float* __restrict__ gs,
    const float* __restrict__ gb, float* __restrict__ X)
{
    __shared__ float red[256];
    int bs = blockIdx.x;
    int sq = bs % S_;
    int id = ids[bs];
    const float* wrow = we + (size_t)id * H_;
    const float* prow = pe + (size_t)sq * H_;
    float z[3];
    #pragma unroll
    for (int r = 0; r < 3; r++) {
        int h = threadIdx.x + 256*r;
        z[r] = wrow[h] + prow[h];
    }
    float sum = z[0] + z[1] + z[2];
    sum = block_reduce_sum256(sum, red);
    float m = sum * (1.0f / H_);
    float vs = 0.f;
    #pragma unroll
    for (int r = 0; r < 3; r++) { float d = z[r]-m; vs += d*d; }
    vs = block_reduce_sum256(vs, red) * (1.0f / H_);
    float rstd = 1.0f / sqrtf(vs + LN_EPS);
    float* out = X + (size_t)bs * H_;
    #pragma unroll
    for (int r = 0; r < 3; r++) {
        int h = threadIdx.x + 256*r;
        out[h] = (z[r]-m)*rstd*gs[h] + gb[h];
    }
}

// ===================== residual + LN (in place into X) =====================
__global__ __launch_bounds__(256) void residual_ln_kernel(
    float* __restrict__ X, const float* __restrict__ Y,
    const float* __restrict__ gs, const float* __restrict__ gb)
{
    __shared__ float red[256];
    int bs = blockIdx.x;
    float* xrow = X + (size_t)bs * H_;
    const float* yrow = Y + (size_t)bs * H_;
    float z[3];
    #pragma unroll
    for (int r = 0; r < 3; r++) {
        int h = threadIdx.x + 256*r;
        z[r] = xrow[h] + yrow[h];
    }
    float sum = z[0] + z[1] + z[2];
    sum = block_reduce_sum256(sum, red);
    float m = sum * (1.0f / H_);
    float vs = 0.f;
    #pragma unroll
    for (int r = 0; r < 3; r++) { float d = z[r]-m; vs += d*d; }
    vs = block_reduce_sum256(vs, red) * (1.0f / H_);
    float rstd = 1.0f / sqrtf(vs + LN_EPS);
    #pragma unroll
    for (int r = 0; r < 3; r++) {
        int h = threadIdx.x + 256*r;
        xrow[h] = (z[r]-m)*rstd*gs[h] + gb[h];
    }
}

// ===================== weight transpose + fp16 hi/lo split =====================
// W [K][N] fp32 row-major  ->  Wt hi/lo [N][K] halves. grid (K/64, N/64, nz)
__global__ __launch_bounds__(256) void wconv_kernel(
    const float* __restrict__ W0, const float* __restrict__ W1,
    const float* __restrict__ W2, int K, int N,
    _Float16* __restrict__ OH, _Float16* __restrict__ OL, long zoff)
{
    __shared__ float t[64][65];
    int z = blockIdx.z;
    const float* W = (z==0) ? W0 : ((z==1) ? W1 : W2);
    OH += (long)z*zoff; OL += (long)z*zoff;
    int k0 = blockIdx.x*64, n0 = blockIdx.y*64;
    int tid = threadIdx.x;
    int lr = tid>>4, lc = (tid&15)*4;
    #pragma unroll
    for (int p = 0; p < 4; p++) {
        float4 v = *(const float4*)&W[(size_t)(k0+lr+16*p)*N + n0 + lc];
        t[lr+16*p][lc]   = v.x; t[lr+16*p][lc+1] = v.y;
        t[lr+16*p][lc+2] = v.z; t[lr+16*p][lc+3] = v.w;
    }
    __syncthreads();
    int n = tid>>2, kb = (tid&3)*16;
    union U { _Float16 h[8]; uint4 u; } h0, h1, l0, l1;
    #pragma unroll
    for (int e = 0; e < 8; e++) {
        float x = t[kb+e][n];
        _Float16 hv = (_Float16)x;
        h0.h[e] = hv; l0.h[e] = (_Float16)(x - (float)hv);
    }
    #pragma unroll
    for (int e = 0; e < 8; e++) {
        float x = t[kb+8+e][n];
        _Float16 hv = (_Float16)x;
        h1.h[e] = hv; l1.h[e] = (_Float16)(x - (float)hv);
    }
    size_t ob = (size_t)(n0+n)*K + k0 + kb;
    *(uint4*)&OH[ob]   = h0.u;
    *(uint4*)&OH[ob+8] = h1.u;
    *(uint4*)&OL[ob]   = l0.u;
    *(uint4*)&OL[ob+8] = l1.u;
}

// ===================== MFMA fp16-split GEMM v2 =====================
// C = act(A @ W + bias [+C]).  A: fp32 (converted in staging) OR pre-split halves.
// Wt: pre-split, pre-transposed [N][K] halves. Out: fp32 C or split halves OH/OL.
// M%128==0, N%128==0, K%32==0.
#define ASTR2 40
__global__ __launch_bounds__(256) void gemm2_kernel(
    const float* __restrict__ A32, const _Float16* __restrict__ AhG,
    const _Float16* __restrict__ AlG, int lda,
    const _Float16* __restrict__ WtH, const _Float16* __restrict__ WtL,
    int ldw, long wz,
    float* __restrict__ C, _Float16* __restrict__ OH, _Float16* __restrict__ OL,
    int ldc, long oz,
    const float* __restrict__ bias0, const float* __restrict__ bias1,
    const float* __restrict__ bias2,
    int M, int N, int K, int flags)
{
    __shared__ __align__(16) _Float16 Ah[128*ASTR2], Al[128*ASTR2];
    __shared__ __align__(16) _Float16 Bh[128*ASTR2], Bl[128*ASTR2];
    int z = blockIdx.z;
    WtH += (long)z*wz; WtL += (long)z*wz;
    if (OH) { OH += (long)z*oz; OL += (long)z*oz; }
    const float* bias = (z==0) ? bias0 : ((z==1) ? bias1 : bias2);
    const int tid = threadIdx.x, lane = tid&63, wid = tid>>6;
    const int wm = wid&1, wn = wid>>1;
    const int l15 = lane&15, quad = lane>>4;
    const int m0 = blockIdx.x*128, n0 = blockIdx.y*128;
    const int am = tid>>1, ak = (tid&1)*16;

    f32x4 acc[4][4];
    #pragma unroll
    for (int i = 0; i < 4; i++)
        #pragma unroll
        for (int j = 0; j < 4; j++)
            acc[i][j] = (f32x4){0.f,0.f,0.f,0.f};

    for (int k0 = 0; k0 < K; k0 += 32) {
        // ---- stage B: pre-split halves, straight 16B copies ----
        {
            const _Float16* bp = &WtH[(size_t)(n0+am)*ldw + k0 + ak];
            *(uint4*)&Bh[am*ASTR2 + ak]     = *(const uint4*)bp;
            *(uint4*)&Bh[am*ASTR2 + ak + 8] = *(const uint4*)(bp+8);
            const _Float16* bq2 = &WtL[(size_t)(n0+am)*ldw + k0 + ak];
            *(uint4*)&Bl[am*ASTR2 + ak]     = *(const uint4*)bq2;
            *(uint4*)&Bl[am*ASTR2 + ak + 8] = *(const uint4*)(bq2+8);
        }
        // ---- stage A ----
        if (A32) {
            const float* ap = &A32[(size_t)(m0+am)*lda + k0 + ak];
            float vv[16];
            *(float4*)&vv[0]  = *(const float4*)ap;
            *(float4*)&vv[4]  = *(const float4*)(ap+4);
            *(float4*)&vv[8]  = *(const float4*)(ap+8);
            *(float4*)&vv[12] = *(const float4*)(ap+12);
            if (flags & GF_RELU_IN) {
                #pragma unroll
                for (int e = 0; e < 16; e++) vv[e] = fmaxf(vv[e], 0.f);
            }
            union U { _Float16 h[8]; uint4 u; } h0, h1, l0, l1;
            #pragma unroll
            for (int e = 0; e < 8; e++) {
                _Float16 hv = (_Float16)vv[e];
                h0.h[e] = hv; l0.h[e] = (_Float16)(vv[e] - (float)hv);
            }
            #pragma unroll
            for (int e = 0; e < 8; e++) {
                _Float16 hv = (_Float16)vv[8+e];
                h1.h[e] = hv; l1.h[e] = (_Float16)(vv[8+e] - (float)hv);
            }
            *(uint4*)&Ah[am*ASTR2 + ak]     = h0.u;
            *(uint4*)&Ah[am*ASTR2 + ak + 8] = h1.u;
            *(uint4*)&Al[am*ASTR2 + ak]     = l0.u;
            *(uint4*)&Al[am*ASTR2 + ak + 8] = l1.u;
        } else {
            const _Float16* ap = &AhG[(size_t)(m0+am)*lda + k0 + ak];
            *(uint4*)&Ah[am*ASTR2 + ak]     = *(const uint4*)ap;
            *(uint4*)&Ah[am*ASTR2 + ak + 8] = *(const uint4*)(ap+8);
            const _Float16* aq = &AlG[(size_t)(m0+am)*lda + k0 + ak];
            *(uint4*)&Al[am*ASTR2 + ak]     = *(const uint4*)aq;
            *(uint4*)&Al[am*ASTR2 + ak + 8] = *(const uint4*)(aq+8);
        }
        __syncthreads();
        half8 afh[4], afl[4], bfh[4], bfl[4];
        #pragma unroll
        for (int i = 0; i < 4; i++) {
            int m = wm*64 + i*16 + l15;
            afh[i] = *(const half8*)&Ah[m*ASTR2 + quad*8];
            afl[i] = *(const half8*)&Al[m*ASTR2 + quad*8];
            int n = wn*64 + i*16 + l15;
            bfh[i] = *(const half8*)&Bh[n*ASTR2 + quad*8];
            bfl[i] = *(const half8*)&Bl[n*ASTR2 + quad*8];
        }
        #pragma unroll
        for (int i = 0; i < 4; i++)
            #pragma unroll
            for (int j = 0; j < 4; j++) {
                acc[i][j] = __builtin_amdgcn_mfma_f32_16x16x32_f16(afh[i], bfh[j], acc[i][j], 0,0,0);
                acc[i][j] = __builtin_amdgcn_mfma_f32_16x16x32_f16(afh[i], bfl[j], acc[i][j], 0,0,0);
                acc[i][j] = __builtin_amdgcn_mfma_f32_16x16x32_f16(afl[i], bfh[j], acc[i][j], 0,0,0);
            }
        __syncthreads();
    }
    // ---- epilogue ----
    #pragma unroll
    for (int i = 0; i < 4; i++)
        #pragma unroll
        for (int j = 0; j < 4; j++)
            #pragma unroll
            for (int r = 0; r < 4; r++) {
                int gm = m0 + wm*64 + i*16 + quad*4 + r;
                int gn = n0 + wn*64 + j*16 + l15;
                float v = acc[i][j][r];
                if (bias) v += bias[gn];
                if (flags & GF_ACCUM) v += C[(size_t)gm*ldc + gn];
                if (flags & GF_RELU_OUT) v = fmaxf(v, 0.f);
                if (flags & GF_GELU_OUT) v = 0.5f*v*(1.0f + erff(v*0.70710678118654752f));
                if (OH) {
                    _Float16 hv = (_Float16)v;
                    OH[(size_t)gm*ldc + gn] = hv;
                    OL[(size_t)gm*ldc + gn] = (_Float16)(v - (float)hv);
                } else {
                    C[(size_t)gm*ldc + gn] = v;
                }
            }
}

// ===================== fp32 GEMM (small head GEMM, N=122) =====================
#define BM 64
#define BN 64
#define BK 16
__global__ __launch_bounds__(256) void gemm_kernel(
    const float* __restrict__ A, int lda,
    const float* __restrict__ W, int ldb,
    float* __restrict__ C, int ldc,
    const float* __restrict__ bias,
    int M, int N, int K, int flags)
{
    __shared__ __align__(16) float As[BK][BM+4];
    __shared__ __align__(16) float Bs[BK][BN+4];
    int tid = threadIdx.x;
    int tx = tid & 15, ty = tid >> 4;
    int m0 = blockIdx.x * BM;
    int n0 = blockIdx.y * BN;
    float acc[4][4] = {};
    for (int k0 = 0; k0 < K; k0 += BK) {
        #pragma unroll
        for (int r = 0; r < 4; r++) {
            int li = tid + 256*r;
            int m  = li >> 4;
            int kk = li & 15;
            int gm = m0 + m, gk = k0 + kk;
            float v = (gm < M && gk < K) ? A[(size_t)gm*lda + gk] : 0.f;
            if (flags & GF_RELU_IN) v = fmaxf(v, 0.f);
            As[kk][m] = v;
        }
        #pragma unroll
        for (int r = 0; r < 4; r++) {
            int li = tid + 256*r;
            int kk = li >> 6;
            int n  = li & 63;
            int gk = k0 + kk, gn = n0 + n;
            Bs[kk][n] = (gk < K && gn < N) ? W[(size_t)gk*ldb + gn] : 0.f;
        }
        __syncthreads();
        #pragma unroll
        for (int kk = 0; kk < BK; kk++) {
            float4 a  = *(const float4*)&As[kk][ty*4];
            float4 bb = *(const float4*)&Bs[kk][tx*4];
            float av[4] = {a.x, a.y, a.z, a.w};
            float bv[4] = {bb.x, bb.y, bb.z, bb.w};
            #pragma unroll
            for (int i = 0; i < 4; i++)
                #pragma unroll
                for (int j = 0; j < 4; j++)
                    acc[i][j] += av[i] * bv[j];
        }
        __syncthreads();
    }
    #pragma unroll
    for (int i = 0; i < 4; i++) {
        int gm = m0 + ty*4 + i;
        if (gm >= M) continue;
        #pragma unroll
        for (int j = 0; j < 4; j++) {
            int gn = n0 + tx*4 + j;
            if (gn >= N) continue;
            float v = acc[i][j];
            if (bias) v += bias[gn];
            if (flags & GF_ACCUM) v += C[(size_t)gm*ldc + gn];
            if (flags & GF_RELU_OUT) v = fmaxf(v, 0.f);
            if (flags & GF_GELU_OUT) v = 0.5f*v*(1.0f + erff(v*0.70710678118654752f));
            C[(size_t)gm*ldc + gn] = v;
        }
    }
}

// ===================== MFMA attention =====================
// One block per (b, head, q-half). 256 threads. 64 KB LDS (union of phases).
__device__ inline int scidx(int row, int col) {
    return row*128 + (((col>>2) ^ (row&7))<<2) + (col&3);
}
__global__ __launch_bounds__(256) void attn2_kernel(
    const _Float16* __restrict__ QhG, const _Float16* __restrict__ QlG,
    const _Float16* __restrict__ KhG, const _Float16* __restrict__ KlG,
    const _Float16* __restrict__ VhG, const _Float16* __restrict__ VlG,
    const int* __restrict__ amask,
    _Float16* __restrict__ Ch, _Float16* __restrict__ Cl)
{
    __shared__ __align__(16) char smem[65536];
    _Float16* Qh_s = (_Float16*)smem;            // [64][72]
    _Float16* Ql_s = Qh_s + 64*72;
    _Float16* Kh_s = Ql_s + 64*72;               // [128][72]
    _Float16* Kl_s = Kh_s + 128*72;
    float*    Sc   = (float*)smem;               // [64][128] swizzled (phase 2)
    _Float16* Vth  = (_Float16*)(smem + 32768);  // [64][128] swizzled
    _Float16* Vtl  = Vth + 64*128;

    int blk = blockIdx.x;
    int qh2 = blk & 1;
    int bh  = blk >> 1;
    int b = bh / NH_, hh = bh % NH_;
    const int tid = threadIdx.x, lane = tid&63, wid = tid>>6;
    const int l15 = lane&15, quad = lane>>4;
    const int qr = wid*16;
    size_t tokb = (size_t)b*S_*H_ + (size_t)hh*DH_;

    // mask values for this lane's 8 column groups
    float nmask[8];
    #pragma unroll
    for (int j = 0; j < 8; j++)
        nmask[j] = (amask[b*S_ + j*16 + l15] > 0) ? 0.f : -1e9f;

    // ---- phase 1 staging: Q (64 rows of this half), K (all 128) ----
    {
        int row = tid>>2, part = (tid&3)*16;
        size_t qg = tokb + (size_t)(qh2*64 + row)*H_ + part;
        *(uint4*)&Qh_s[row*72 + part] = *(const uint4*)(QhG + qg);
        *(uint4*)&Ql_s[row*72 + part] = *(const uint4*)(QlG + qg);
        #pragma unroll
        for (int p = 0; p < 2; p++) {
            int krow = row + p*64;
            size_t kg = tokb + (size_t)krow*H_ + part;
            *(uint4*)&Kh_s[krow*72 + part] = *(const uint4*)(KhG + kg);
            *(uint4*)&Kl_s[krow*72 + part] = *(const uint4*)(KlG + kg);
        }
    }
    __syncthreads();

    // ---- phase 1: S = Q K^T (each wave: 16 q rows x 128 keys) ----
    f32x4 acc1[8];
    #pragma unroll
    for (int j = 0; j < 8; j++) acc1[j] = (f32x4){0.f,0.f,0.f,0.f};
    half8 aqh[2], aql[2];
    #pragma unroll
    for (int kc = 0; kc < 2; kc++) {
        aqh[kc] = *(const half8*)&Qh_s[(qr + l15)*72 + kc*32 + quad*8];
        aql[kc] = *(const half8*)&Ql_s[(qr + l15)*72 + kc*32 + quad*8];
    }
    #pragma unroll
    for (int j = 0; j < 8; j++) {
        #pragma unroll
        for (int kc = 0; kc < 2; kc++) {
            half8 bkh = *(const half8*)&Kh_s[(j*16 + l15)*72 + kc*32 + quad*8];
            half8 bkl = *(const half8*)&Kl_s[(j*16 + l15)*72 + kc*32 + quad*8];
            acc1[j] = __builtin_amdgcn_mfma_f32_16x16x32_f16(aqh[kc], bkh, acc1[j], 0,0,0);
            acc1[j] = __builtin_amdgcn_mfma_f32_16x16x32_f16(aqh[kc], bkl, acc1[j], 0,0,0);
            acc1[j] = __builtin_amdgcn_mfma_f32_16x16x32_f16(aql[kc], bkh, acc1[j], 0,0,0);
        }
    }
    __syncthreads();   // all waves done reading Q/K LDS

    // ---- write S (scaled+masked) to swizzled Sc; stage V transposed ----
    #pragma unroll
    for (int j = 0; j < 8; j++)
        #pragma unroll
        for (int r = 0; r < 4; r++) {
            int row = qr + quad*4 + r;
            int col = j*16 + l15;
            Sc[scidx(row, col)] = acc1[j][r]*INV_SQRT_DH + nmask[j];
        }
    {
        int key = tid>>1, dh = (tid&1)*32;
        union V32 { _Float16 h[32]; uint4 u[4]; } bufh, bufl;
        #pragma unroll
        for (int e = 0; e < 4; e++) {
            bufh.u[e] = *(const uint4*)(VhG + tokb + (size_t)key*H_ + dh + e*8);
            bufl.u[e] = *(const uint4*)(VlG + tokb + (size_t)key*H_ + dh + e*8);
        }
        int kg = key>>3, kr = key&7;
        #pragma unroll
        for (int e = 0; e < 32; e++) {
            int d = dh + e;
            int pos = kg ^ (d & 7);
            Vth[d*128 + pos*8 + kr] = bufh.h[e];
            Vtl[d*128 + pos*8 + kr] = bufl.h[e];
        }
    }
    __syncthreads();

    // ---- softmax over keys (4 threads per row, shfl combine) ----
    {
        int row = tid>>2, part = (tid&3)*32;
        float mx = -INFINITY;
        #pragma unroll 8
        for (int e = 0; e < 32; e++)
            mx = fmaxf(mx, Sc[scidx(row, part+e)]);
        mx = fmaxf(mx, __shfl_xor(mx, 1));
        mx = fmaxf(mx, __shfl_xor(mx, 2));
        float s = 0.f;
        #pragma unroll 8
        for (int e = 0; e < 32; e++) {
            int idx = scidx(row, part+e);
            float ev = expf(Sc[idx] - mx);
            Sc[idx] = ev; s += ev;
        }
        s += __shfl_xor(s, 1);
        s += __shfl_xor(s, 2);
        float inv = 1.0f / s;
        #pragma unroll 8
        for (int e = 0; e < 32; e++)
            Sc[scidx(row, part+e)] *= inv;
    }
    __syncthreads();

    // ---- phase 2: ctx = P V ----
    f32x4 acc2[4];
    #pragma unroll
    for (int jd = 0; jd < 4; jd++) acc2[jd] = (f32x4){0.f,0.f,0.f,0.f};
    #pragma unroll
    for (int kc = 0; kc < 4; kc++) {
        int q = qr + l15;
        int g16 = kc*8 + quad*2;
        float4 p0 = *(const float4*)&Sc[q*128 + ((g16   ^ (q&7))<<2)];
        float4 p1 = *(const float4*)&Sc[q*128 + (((g16+1) ^ (q&7))<<2)];
        float pv[8] = {p0.x,p0.y,p0.z,p0.w, p1.x,p1.y,p1.z,p1.w};
        union U { _Float16 h[8]; half8 v; } ph, pl;
        #pragma unroll
        for (int e = 0; e < 8; e++) {
            _Float16 hv = (_Float16)pv[e];
            ph.h[e] = hv; pl.h[e] = (_Float16)(pv[e] - (float)hv);
        }
        #pragma unroll
        for (int jd = 0; jd < 4; jd++) {
            int n = jd*16 + l15;
            int pos = (kc*4 + quad) ^ (n & 7);
            half8 vh = *(const half8*)&Vth[n*128 + pos*8];
            half8 vl = *(const half8*)&Vtl[n*128 + pos*8];
            acc2[jd] = __builtin_amdgcn_mfma_f32_16x16x32_f16(ph.v, vh, acc2[jd], 0,0,0);
            acc2[jd] = __builtin_amdgcn_mfma_f32_16x16x32_f16(ph.v, vl, acc2[jd], 0,0,0);
            acc2[jd] = __builtin_amdgcn_mfma_f32_16x16x32_f16(pl.v, vh, acc2[jd], 0,0,0);
        }
    }
    // ---- epilogue: split halves out ----
    #pragma unroll
    for (int jd = 0; jd < 4; jd++)
        #pragma unroll
        for (int r = 0; r < 4; r++) {
            int row = qr + quad*4 + r;
            int token = b*S_ + qh2*64 + row;
            int d = jd*16 + l15;
            float v = acc2[jd][r];
            _Float16 hv = (_Float16)v;
            Ch[(size_t)token*H_ + hh*DH_ + d] = hv;
            Cl[(size_t)token*H_ + hh*DH_ + d] = (_Float16)(v - (float)hv);
        }
}

// ===================== intent head =====================
__global__ __launch_bounds__(64) void intent_kernel(
    const float* __restrict__ X, const float* __restrict__ iW1,
    const float* __restrict__ ib1, const float* __restrict__ iW2,
    const float* __restrict__ ib2, const int* __restrict__ tgt,
    float* __restrict__ iloss, float* __restrict__ outf)
{
    int b = blockIdx.x; int j = threadIdx.x;
    __shared__ float h1[64];
    __shared__ float lg[32];
    const float* x0 = X + (size_t)b*S_*H_;
    float acc = ib1[j];
    for (int h = 0; h < H_; h++) acc += fmaxf(x0[h], 0.f) * iW1[(size_t)h*64 + j];
    h1[j] = fmaxf(acc, 0.f);
    __syncthreads();
    if (j < INTENT_) {
        float l = ib2[j];
        for (int k = 0; k < 64; k++) l += h1[k]*iW2[k*INTENT_ + j];
        lg[j] = l;
    }
    __syncthreads();
    if (j == 0) {
        float mx = -INFINITY; int bi = 0;
        for (int c = 0; c < INTENT_; c++) if (lg[c] > mx) { mx = lg[c]; bi = c; }
        float sm = 0.f;
        for (int c = 0; c < INTENT_; c++) sm += expf(lg[c]-mx);
        float lse = mx + logf(sm);
        iloss[b] = lse - lg[tgt[b]];
        outf[1 + (size_t)NT_ + b] = (float)bi;
    }
}

// ===================== CRF log-likelihood (per batch) =====================
#define TSTR 124
__global__ __launch_bounds__(128) void crf_llh_kernel(
    const float* __restrict__ E_, const int* __restrict__ tags,
    const int* __restrict__ mask, const float* __restrict__ start,
    const float* __restrict__ endv, const float* __restrict__ trans,
    float* __restrict__ crfv)
{
    int b = blockIdx.x; int j = threadIdx.x;
    __shared__ __align__(16) float etT[TAGS_*TSTR];
    __shared__ __align__(16) float alpha[TAGS_];
    __shared__ __align__(16) float ealpha[TAGS_];
    __shared__ __align__(16) float red[128];
    const float* E = E_ + (size_t)b*S_*TAGS_;
    for (int i = 0; i < TAGS_; i++)
        if (j < TAGS_) etT[(size_t)j*TSTR + i] = expf(trans[i*TAGS_ + j]);
    if (j < TAGS_) alpha[j] = start[j] + E[j];
    __syncthreads();

    for (int t = 1; t < S_; t++) {
        float av = (j < TAGS_) ? alpha[j] : -1e30f;
        red[j] = av; __syncthreads();
        for (int off = 64; off > 0; off >>= 1) {
            if (j < off) red[j] = fmaxf(red[j], red[j+off]);
            __syncthreads();
        }
        float mx = red[0];
        if (j < TAGS_) ealpha[j] = expf(av - mx);
        __syncthreads();
        float nv = 0.f;
        int m_t = mask[b*S_ + t];
        if (j < TAGS_) {
            const float* tr = &etT[(size_t)j*TSTR];
            float s = 0.f;
            #pragma unroll 5
            for (int i = 0; i < 120; i += 4) {
                float4 ea = *(const float4*)&ealpha[i];
                float4 tt = *(const float4*)&tr[i];
                s += ea.x*tt.x + ea.y*tt.y + ea.z*tt.z + ea.w*tt.w;
            }
            s += ealpha[120]*tr[120] + ealpha[121]*tr[121];
            nv = mx + logf(s) + E[t*TAGS_ + j];
        }
        __syncthreads();
        if (j < TAGS_ && m_t) alpha[j] = nv;
        __syncthreads();
    }

    int tg  = (j < S_) ? tags[b*S_ + j] : 0;
    int mk  = (j < S_) ? mask[b*S_ + j] : 0;
    int tgp = (j >= 1 && j < S_) ? tags[b*S_ + j - 1] : 0;
    float term = 0.f;
    if (j >= 1 && j < S_ && mk)
        term = trans[tgp*TAGS_ + tg] + E[(size_t)j*TAGS_ + tg];
    red[j] = term; __syncthreads();
    for (int off = 64; off > 0; off >>= 1) {
        if (j < off) red[j] += red[j+off];
        __syncthreads();
    }
    float numsum = red[0]; __syncthreads();
    red[j] = (float)mk; __syncthreads();
    for (int off = 64; off > 0; off >>= 1) {
        if (j < off) red[j] += red[j+off];
        __syncthreads();
    }
    int msum = (int)red[0]; __syncthreads();
    float dv = (j < TAGS_) ? alpha[j] + endv[j] : -1e30f;
    red[j] = dv; __syncthreads();
    for (int off = 64; off > 0; off >>= 1) {
        if (j < off) red[j] = fmaxf(red[j], red[j+off]);
        __syncthreads();
    }
    float dmx = red[0]; __syncthreads();
    red[j] = (j < TAGS_) ? expf(dv - dmx) : 0.f;
    __syncthreads();
    for (int off = 64; off > 0; off >>= 1) {
        if (j < off) red[j] += red[j+off];
        __syncthreads();
    }
    if (j == 0) {
        float denom = dmx + logf(red[0]);
        int tag0 = tags[b*S_];
        int last_tag = tags[b*S_ + (msum - 1)];
        float num = start[tag0] + E[tag0] + numsum + endv[last_tag];
        crfv[b] = num - denom;
    }
}

// ===================== Viterbi decode (per batch) =====================
__global__ __launch_bounds__(128) void viterbi_kernel(
    const float* __restrict__ E_, const int* __restrict__ mask,
    const float* __restrict__ start, const float* __restrict__ endv,
    const float* __restrict__ trans, int* __restrict__ BP,
    float* __restrict__ outf)
{
    int b = blockIdx.x; int j = threadIdx.x;
    __shared__ __align__(16) float tT[TAGS_*TSTR];
    __shared__ __align__(16) float alpha[TAGS_];
    const float* E = E_ + (size_t)b*S_*TAGS_;
    for (int i = 0; i < TAGS_; i++)
        if (j < TAGS_) tT[(size_t)j*TSTR + i] = trans[i*TAGS_ + j];
    if (j < TAGS_) alpha[j] = start[j] + E[j];
    __syncthreads();
    for (int t = 1; t < S_; t++) {
        int m_t = mask[b*S_ + t];
        float nv = 0.f; int nb = 0;
        if (j < TAGS_) {
            const float* tr = &tT[(size_t)j*TSTR];
            float best = -1e30f; int bi = 0;
            #pragma unroll 5
            for (int i = 0; i < 120; i += 4) {
                float4 al = *(const float4*)&alpha[i];
                float4 tt = *(const float4*)&tr[i];
                float v0 = al.x + tt.x; if (v0 > best) { best = v0; bi = i;   }
                float v1 = al.y + tt.y; if (v1 > best) { best = v1; bi = i+1; }
                float v2 = al.z + tt.z; if (v2 > best) { best = v2; bi = i+2; }
                float v3 = al.w + tt.w; if (v3 > best) { best = v3; bi = i+3; }
            }
            { float v = alpha[120] + tr[120]; if (v > best) { best = v; bi = 120; } }
            { float v = alpha[121] + tr[121]; if (v > best) { best = v; bi = 121; } }
            if (m_t) { nv = best + E[(size_t)t*TAGS_ + j]; nb = bi; }
            else     { nv = alpha[j];                       nb = j;  }
        }
        __syncthreads();
        if (j < TAGS_) {
            alpha[j] = nv;
            BP[((size_t)b*(S_-1) + (t-1))*TAGS_ + j] = nb;
        }
        __syncthreads();
    }
    if (j == 0) {
        float best = -1e30f; int bi = 0;
        for (int i = 0; i < TAGS_; i++) {
            float v = alpha[i] + endv[i];
            if (v > best) { best = v; bi = i; }
        }
        int tag = bi;
        outf[1 + (size_t)b*S_ + (S_-1)] = (float)tag;
        for (int t = S_-1; t >= 1; t--) {
            tag = BP[((size_t)b*(S_-1) + (t-1))*TAGS_ + tag];
            outf[1 + (size_t)b*S_ + (t-1)] = (float)tag;
        }
    }
}

// ===================== final joint loss =====================
__global__ void combine_kernel(const float* __restrict__ iloss,
                               const float* __restrict__ crfv,
                               const float* __restrict__ lv,
                               float* __restrict__ outf)
{
    if (threadIdx.x == 0 && blockIdx.x == 0) {
        float si = 0.f, sc = 0.f;
        for (int b = 0; b < B_; b++) { si += iloss[b]; sc += crfv[b]; }
        float p1 = expf(-lv[0]), p2 = expf(-lv[1]);
        float slots_loss = -sc;
        outf[0] = p1*si + (float)B_*lv[0] + p2*slots_loss + lv[1];
    }
}

// ===================== host launch =====================
extern "C" void kernel_launch(void* const* d_in, const int* in_sizes, int n_in,
                              void* d_out, int out_size, void* d_ws, size_t ws_size,
                              hipStream_t stream) {
    const int*   ids   = (const int*)  d_in[0];
    const int*   amask = (const int*)  d_in[1];
    const int*   itgt  = (const int*)  d_in[2];
    const int*   stgt  = (const int*)  d_in[3];
    const int*   smask = (const int*)  d_in[4];
    const float* we    = (const float*)d_in[5];
    const float* pe    = (const float*)d_in[6];
    const float* embs  = (const float*)d_in[7];
    const float* embb  = (const float*)d_in[8];
    const float* Wq    = (const float*)d_in[9];
    const float* bq    = (const float*)d_in[10];
    const float* Wk    = (const float*)d_in[11];
    const float* bk    = (const float*)d_in[12];
    const float* Wv    = (const float*)d_in[13];
    const float* bv    = (const float*)d_in[14];
    const float* Wo    = (const float*)d_in[15];
    const float* bo    = (const float*)d_in[16];
    const float* sas   = (const float*)d_in[17];
    const float* sab   = (const float*)d_in[18];
    const float* W1f   = (const float*)d_in[19];
    const float* b1f   = (const float*)d_in[20];
    const float* W2f   = (const float*)d_in[21];
    const float* b2f   = (const float*)d_in[22];
    const float* ols   = (const float*)d_in[23];
    const float* olb   = (const float*)d_in[24];
    const float* iW1   = (const float*)d_in[25];
    const float* ib1   = (const float*)d_in[26];
    const float* iW2   = (const float*)d_in[27];
    const float* ib2   = (const float*)d_in[28];
    const float* sW1   = (const float*)d_in[29];
    const float* sb1   = (const float*)d_in[30];
    const float* sW2   = (const float*)d_in[31];
    const float* sb2   = (const float*)d_in[32];
    const float* crfs  = (const float*)d_in[33];
    const float* crfe  = (const float*)d_in[34];
    const float* crft  = (const float*)d_in[35];
    const float* lv    = (const float*)d_in[36];

    float* outf = (float*)d_out;
    float* wsf  = (float*)d_ws;
    const long NBf = (long)NT_ * H_;             // 6,291,456
    const long NTH = NBf;                        // halves per activation tensor
    const long HH  = (long)H_ * H_;              // 589,824
    const long WCAP = 2359296;                   // floats per weight scratch region

    float*     X   = wsf;
    _Float16*  qh  = (_Float16*)(wsf + NBf);     // 3*NBf floats worth of halves
    _Float16 *Qh = qh,        *Ql = qh + NTH,
             *Kh = qh + 2*NTH,*Kl = qh + 3*NTH,
             *Vh = qh + 4*NTH,*Vl = qh + 5*NTH;
    _Float16 *Fh = qh, *Fl = qh + (long)NT_*1536;   // FF intermediate (reuse)
    float*     H1     = (float*)(wsf + NBf);        // heads (reuse)
    float*     logits = H1 + (long)NT_*256;
    int*       BP     = (int*)(logits + (long)NT_*122);
    _Float16*  Ch  = (_Float16*)(wsf + 4*NBf);
    _Float16*  Cl  = Ch + NTH;
    float*     Yb  = wsf + 5*NBf;
    _Float16*  WAh = (_Float16*)(wsf + 6*NBf);      // capacity 2*WCAP halves
    _Float16*  WBh = (_Float16*)(wsf + 6*NBf + WCAP);
    float*     iloss = wsf + 6*NBf + 2*WCAP;
    float*     crfv  = iloss + 64;

    auto wconv = [&](const float* w0, const float* w1, const float* w2,
                     int K, int N, _Float16* oh, _Float16* ol, long zoff, int nz) {
        dim3 g(K/64, N/64, nz);
        hipLaunchKernelGGL(wconv_kernel, g, dim3(256), 0, stream,
                           w0, w1, w2, K, N, oh, ol, zoff);
    };
    auto g2 = [&](const float* A32, const _Float16* AhG, const _Float16* AlG, int lda,
                  const _Float16* WtH, const _Float16* WtL, int ldw, long wz,
                  float* C, _Float16* OH, _Float16* OL, int ldc, long oz,
                  const float* b0, const float* b1, const float* b2,
                  int M, int N, int K, int flags, int nz) {
        dim3 g(M/128, N/128, nz);
        hipLaunchKernelGGL(gemm2_kernel, g, dim3(256), 0, stream,
                           A32, AhG, AlG, lda, WtH, WtL, ldw, wz,
                           C, OH, OL, ldc, oz, b0, b1, b2, M, N, K, flags);
    };

    hipLaunchKernelGGL(embed_ln_kernel, dim3(NT_), dim3(256), 0, stream,
                       ids, we, pe, embs, embb, X);

    for (int i = 0; i < L_; i++) {
        const long WO = (long)i*HH;
        // QKV (batched z=3): weights -> WA
        wconv(Wq + WO, Wk + WO, Wv + WO, H_, H_, WAh, WAh + 3*HH, HH, 3);
        g2(X, nullptr, nullptr, H_, WAh, WAh + 3*HH, H_, HH,
           nullptr, Qh, Ql, H_, 2*NTH,
           bq + i*H_, bk + i*H_, bv + i*H_, NT_, H_, H_, 0, 3);
        // attention
        hipLaunchKernelGGL(attn2_kernel, dim3(B_*NH_*2), dim3(256), 0, stream,
                           Qh, Ql, Kh, Kl, Vh, Vl, amask, Ch, Cl);
        // O-proj: Wo -> WB
        wconv(Wo + WO, Wo + WO, Wo + WO, H_, H_, WBh, WBh + HH, 0, 1);
        g2(nullptr, Ch, Cl, H_, WBh, WBh + HH, H_, 0,
           Yb, nullptr, nullptr, H_, 0,
           bo + i*H_, nullptr, nullptr, NT_, H_, H_, 0, 1);
        hipLaunchKernelGGL(residual_ln_kernel, dim3(NT_), dim3(256), 0, stream,
                           X, Yb, sas + i*H_, sab + i*H_);
        // FF: W1f -> WA ([3072][768]), W2f -> WB ([768][3072])
        wconv(W1f + (long)i*H_*FF_, nullptr, nullptr, H_, FF_, WAh, WAh + WCAP, 0, 1);
        wconv(W2f + (long)i*FF_*H_, nullptr, nullptr, FF_, H_, WBh, WBh + WCAP, 0, 1);
        for (int c = 0; c < 2; c++) {
            const int CW = FF_/2;   // 1536
            g2(X, nullptr, nullptr, H_,
               WAh + (long)c*CW*H_, WAh + WCAP + (long)c*CW*H_, H_, 0,
               nullptr, Fh, Fl, CW, 0,
               b1f + (long)i*FF_ + c*CW, nullptr, nullptr,
               NT_, CW, H_, GF_GELU_OUT, 1);
            g2(nullptr, Fh, Fl, CW,
               WBh + (long)c*CW, WBh + WCAP + (long)c*CW, FF_, 0,
               Yb, nullptr, nullptr, H_, 0,
               (c == 0) ? (b2f + i*H_) : nullptr, nullptr, nullptr,
               NT_, H_, CW, (c == 0) ? 0 : GF_ACCUM, 1);
        }
        hipLaunchKernelGGL(residual_ln_kernel, dim3(NT_), dim3(256), 0, stream,
                           X, Yb, ols + i*H_, olb + i*H_);
    }

    hipLaunchKernelGGL(intent_kernel, dim3(B_), dim3(64), 0, stream,
                       X, iW1, ib1, iW2, ib2, itgt, iloss, outf);

    // slots head: H1 = relu(relu(X)@sW1 + sb1); logits = H1@sW2 + sb2
    wconv(sW1, nullptr, nullptr, H_, 256, WAh, WAh + (long)256*H_, 0, 1);
    g2(X, nullptr, nullptr, H_, WAh, WAh + (long)256*H_, H_, 0,
       H1, nullptr, nullptr, 256, 0,
       sb1, nullptr, nullptr, NT_, 256, H_, GF_RELU_IN | GF_RELU_OUT, 1);
    {
        dim3 g((NT_+BM-1)/BM, (TAGS_+BN-1)/BN);
        hipLaunchKernelGGL(gemm_kernel, g, dim3(256), 0, stream,
                           H1, 256, sW2, TAGS_, logits, TAGS_, sb2,
                           NT_, TAGS_, 256, 0);
    }

    hipLaunchKernelGGL(crf_llh_kernel, dim3(B_), dim3(128), 0, stream,
                       logits, stgt, smask, crfs, crfe, crft, crfv);
    hipLaunchKernelGGL(viterbi_kernel, dim3(B_), dim3(128), 0, stream,
                       logits, smask, crfs, crfe, crft, BP, outf);

    hipLaunchKernelGGL(combine_kernel, dim3(1), dim3(64), 0, stream,
                       iloss, crfv, lv, outf);
}

// Round 4
// 4890.044 us; speedup vs baseline: 5.5304x; 1.0028x over previous
//
#include <hip/hip_runtime.h>
#include <math.h>
#include <stdint.h>

// ---- problem constants ----
#define B_      64
#define S_      128
#define H_      768
#define L_      6
#define NH_     12
#define DH_     64
#define FF_     3072
#define INTENT_ 22
#define TAGS_   122
#define NT_     (B_*S_)          // 8192 tokens
#define LN_EPS  1e-12f
#define INV_SQRT_DH 0.125f

#define GF_RELU_OUT 2
#define GF_GELU_OUT 4
#define GF_ADDRES   16   // add residual from Rh/Rl halves
#define GF_ACCH     32   // accumulate from current OH/OL contents

typedef _Float16 half8 __attribute__((ext_vector_type(8)));
typedef float    f32x4 __attribute__((ext_vector_type(4)));

// ===================== async global->LDS 16B =====================
__device__ __forceinline__ void gld16(const _Float16* g, _Float16* l) {
    __builtin_amdgcn_global_load_lds(
        (const __attribute__((address_space(1))) unsigned int*)(uintptr_t)g,
        (__attribute__((address_space(3))) unsigned int*)(unsigned int)(uintptr_t)l,
        16, 0, 0);
}

__device__ inline float wave_max(float v){
    #pragma unroll
    for (int d = 32; d; d >>= 1) v = fmaxf(v, __shfl_xor(v, d));
    return v;
}
__device__ inline float wave_sum(float v){
    #pragma unroll
    for (int d = 32; d; d >>= 1) v += __shfl_xor(v, d);
    return v;
}

// ===================== embedding + LN -> split halves =====================
__global__ __launch_bounds__(256) void embed_ln_kernel(
    const int* __restrict__ ids, const float* __restrict__ we,
    const float* __restrict__ pe, const float* __restrict__ gs,
    const float* __restrict__ gb, _Float16* __restrict__ Xh,
    _Float16* __restrict__ Xl)
{
    __shared__ float red[256];
    int bs = blockIdx.x;
    int sq = bs % S_;
    int id = ids[bs];
    int tid = threadIdx.x;
    const float* wrow = we + (size_t)id * H_;
    const float* prow = pe + (size_t)sq * H_;
    float z[3];
    #pragma unroll
    for (int r = 0; r < 3; r++) {
        int h = tid + 256*r;
        z[r] = wrow[h] + prow[h];
    }
    float sum = z[0]+z[1]+z[2];
    red[tid] = sum; __syncthreads();
    for (int off = 128; off > 0; off >>= 1) {
        if (tid < off) red[tid] += red[tid+off];
        __syncthreads();
    }
    float m = red[0] * (1.0f/H_); __syncthreads();
    float vs = 0.f;
    #pragma unroll
    for (int r = 0; r < 3; r++) { float d = z[r]-m; vs += d*d; }
    red[tid] = vs; __syncthreads();
    for (int off = 128; off > 0; off >>= 1) {
        if (tid < off) red[tid] += red[tid+off];
        __syncthreads();
    }
    float rstd = 1.0f / sqrtf(red[0]*(1.0f/H_) + LN_EPS);
    #pragma unroll
    for (int r = 0; r < 3; r++) {
        int h = tid + 256*r;
        float val = (z[r]-m)*rstd*gs[h] + gb[h];
        _Float16 hv = (_Float16)val;
        Xh[(size_t)bs*H_ + h] = hv;
        Xl[(size_t)bs*H_ + h] = (_Float16)(val - (float)hv);
    }
}

// ===================== LN over sum-halves -> split halves (+relu copy) ====
__global__ __launch_bounds__(384) void ln2_kernel(
    const _Float16* __restrict__ Sh, const _Float16* __restrict__ Sl,
    const float* __restrict__ gs, const float* __restrict__ gb,
    _Float16* __restrict__ Xh, _Float16* __restrict__ Xl,
    _Float16* __restrict__ Rh, _Float16* __restrict__ Rl)
{
    __shared__ float red[512];
    int bs = blockIdx.x, tid = threadIdx.x;
    size_t base = (size_t)bs*H_ + tid*2;
    union UU { _Float16 h[2]; unsigned u; };
    UU uh, ul;
    uh.u = *(const unsigned*)(Sh + base);
    ul.u = *(const unsigned*)(Sl + base);
    float z0 = (float)uh.h[0] + (float)ul.h[0];
    float z1 = (float)uh.h[1] + (float)ul.h[1];
    red[tid] = z0 + z1;
    if (tid < 128) red[384+tid] = 0.f;
    __syncthreads();
    for (int off = 256; off > 0; off >>= 1) {
        if (tid < off) red[tid] += red[tid+off];
        __syncthreads();
    }
    float m = red[0] * (1.0f/H_);
    __syncthreads();
    float d0 = z0-m, d1 = z1-m;
    red[tid] = d0*d0 + d1*d1;
    if (tid < 128) red[384+tid] = 0.f;
    __syncthreads();
    for (int off = 256; off > 0; off >>= 1) {
        if (tid < off) red[tid] += red[tid+off];
        __syncthreads();
    }
    float rstd = 1.0f / sqrtf(red[0]*(1.0f/H_) + LN_EPS);
    float2 gv = *(const float2*)(gs + tid*2);
    float2 bv = *(const float2*)(gb + tid*2);
    float v0 = d0*rstd*gv.x + bv.x;
    float v1 = d1*rstd*gv.y + bv.y;
    UU oh, ol;
    oh.h[0] = (_Float16)v0; ol.h[0] = (_Float16)(v0 - (float)oh.h[0]);
    oh.h[1] = (_Float16)v1; ol.h[1] = (_Float16)(v1 - (float)oh.h[1]);
    *(unsigned*)(Xh + base) = oh.u;
    *(unsigned*)(Xl + base) = ol.u;
    if (Rh) {
        float r0 = fmaxf(v0, 0.f), r1 = fmaxf(v1, 0.f);
        UU rh, rl;
        rh.h[0] = (_Float16)r0; rl.h[0] = (_Float16)(r0 - (float)rh.h[0]);
        rh.h[1] = (_Float16)r1; rl.h[1] = (_Float16)(r1 - (float)rh.h[1]);
        *(unsigned*)(Rh + base) = rh.u;
        *(unsigned*)(Rl + base) = rl.u;
    }
}

// ===================== weight transpose + fp16 hi/lo split =====================
// W [K][N] fp32 row-major -> Wt hi/lo [N][K] halves. grid (K/64, N/64, nz)
__global__ __launch_bounds__(256) void wconv_kernel(
    const float* __restrict__ W0, const float* __restrict__ W1,
    const float* __restrict__ W2, const float* __restrict__ W3,
    int K, int N, _Float16* __restrict__ OH, _Float16* __restrict__ OL, long zoff)
{
    __shared__ float t[64][65];
    int z = blockIdx.z;
    const float* W = (z==0) ? W0 : ((z==1) ? W1 : ((z==2) ? W2 : W3));
    OH += (long)z*zoff; OL += (long)z*zoff;
    int k0 = blockIdx.x*64, n0 = blockIdx.y*64;
    int tid = threadIdx.x;
    int lr = tid>>4, lc = (tid&15)*4;
    #pragma unroll
    for (int p = 0; p < 4; p++) {
        float4 v = *(const float4*)&W[(size_t)(k0+lr+16*p)*N + n0 + lc];
        t[lr+16*p][lc]   = v.x; t[lr+16*p][lc+1] = v.y;
        t[lr+16*p][lc+2] = v.z; t[lr+16*p][lc+3] = v.w;
    }
    __syncthreads();
    int n = tid>>2, kb = (tid&3)*16;
    union U { _Float16 h[8]; uint4 u; } h0, h1, l0, l1;
    #pragma unroll
    for (int e = 0; e < 8; e++) {
        float x = t[kb+e][n];
        _Float16 hv = (_Float16)x;
        h0.h[e] = hv; l0.h[e] = (_Float16)(x - (float)hv);
    }
    #pragma unroll
    for (int e = 0; e < 8; e++) {
        float x = t[kb+8+e][n];
        _Float16 hv = (_Float16)x;
        h1.h[e] = hv; l1.h[e] = (_Float16)(x - (float)hv);
    }
    size_t ob = (size_t)(n0+n)*K + k0 + kb;
    *(uint4*)&OH[ob]   = h0.u;
    *(uint4*)&OH[ob+8] = h1.u;
    *(uint4*)&OL[ob]   = l0.u;
    *(uint4*)&OL[ob+8] = l1.u;
}

// ===================== MFMA fp16-split GEMM v3 (global_load_lds staging) ====
// All inputs pre-split halves. M fixed by grid.x*128, N by grid.y*128, K param.
__global__ __launch_bounds__(256) void gemm3_kernel(
    const _Float16* __restrict__ AhG, const _Float16* __restrict__ AlG, int lda,
    const _Float16* __restrict__ WtHb, const _Float16* __restrict__ WtLb,
    int ldw, long wz,
    float* __restrict__ C, _Float16* __restrict__ OHb, _Float16* __restrict__ OLb,
    int ldc, long oz,
    const _Float16* __restrict__ Rh, const _Float16* __restrict__ Rl, int ldr,
    const float* __restrict__ bias0, const float* __restrict__ bias1,
    const float* __restrict__ bias2,
    int K, int flags)
{
    __shared__ __align__(16) _Float16 Ah[128*32], Al[128*32];
    __shared__ __align__(16) _Float16 Bh[128*32], Bl[128*32];
    const int z = blockIdx.z;
    const _Float16* WtH = WtHb + (long)z*wz;
    const _Float16* WtL = WtLb + (long)z*wz;
    _Float16* oh = OHb ? OHb + (long)z*oz : (_Float16*)0;
    _Float16* ol = OLb ? OLb + (long)z*oz : (_Float16*)0;
    const float* bias = (z==0) ? bias0 : ((z==1) ? bias1 : bias2);
    const int tid = threadIdx.x, lane = tid&63, wid = tid>>6;
    const int wm = wid&1, wn = wid>>1;
    const int l15 = lane&15, quad = lane>>4;
    const int m0 = blockIdx.x*128, n0 = blockIdx.y*128;

    // staging assignment: wave 0->Ah, 1->Al, 2->Bh, 3->Bl
    const _Float16* gsrc; _Float16* lbuf; int ld_s; int r0;
    if (wid == 0)      { gsrc = AhG; lbuf = Ah; ld_s = lda; r0 = m0; }
    else if (wid == 1) { gsrc = AlG; lbuf = Al; ld_s = lda; r0 = m0; }
    else if (wid == 2) { gsrc = WtH; lbuf = Bh; ld_s = ldw; r0 = n0; }
    else               { gsrc = WtL; lbuf = Bl; ld_s = ldw; r0 = n0; }
    const _Float16* gbase = gsrc + (size_t)(r0 + (lane>>2))*ld_s + (lane&3)*8;

    f32x4 acc[4][4];
    #pragma unroll
    for (int i = 0; i < 4; i++)
        #pragma unroll
        for (int j = 0; j < 4; j++)
            acc[i][j] = (f32x4){0.f,0.f,0.f,0.f};

    for (int k0 = 0; k0 < K; k0 += 32) {
        #pragma unroll
        for (int q = 0; q < 8; q++)
            gld16(gbase + (size_t)(q*16)*ld_s + k0, lbuf + q*512);
        __syncthreads();
        half8 afh[4], afl[4], bfh[4], bfl[4];
        #pragma unroll
        for (int i = 0; i < 4; i++) {
            int m = wm*64 + i*16 + l15;
            afh[i] = *(const half8*)&Ah[m*32 + quad*8];
            afl[i] = *(const half8*)&Al[m*32 + quad*8];
            int n = wn*64 + i*16 + l15;
            bfh[i] = *(const half8*)&Bh[n*32 + quad*8];
            bfl[i] = *(const half8*)&Bl[n*32 + quad*8];
        }
        #pragma unroll
        for (int i = 0; i < 4; i++)
            #pragma unroll
            for (int j = 0; j < 4; j++) {
                acc[i][j] = __builtin_amdgcn_mfma_f32_16x16x32_f16(afh[i], bfh[j], acc[i][j], 0,0,0);
                acc[i][j] = __builtin_amdgcn_mfma_f32_16x16x32_f16(afh[i], bfl[j], acc[i][j], 0,0,0);
                acc[i][j] = __builtin_amdgcn_mfma_f32_16x16x32_f16(afl[i], bfh[j], acc[i][j], 0,0,0);
            }
        __syncthreads();
    }
    // ---- epilogue: C/D layout col=lane&15, row=quad*4+reg ----
    #pragma unroll
    for (int i = 0; i < 4; i++)
        #pragma unroll
        for (int j = 0; j < 4; j++)
            #pragma unroll
            for (int r = 0; r < 4; r++) {
                int gm = m0 + wm*64 + i*16 + quad*4 + r;
                int gn = n0 + wn*64 + j*16 + l15;
                float v = acc[i][j][r];
                if (bias) v += bias[gn];
                size_t ox = (size_t)gm*ldc + gn;
                if (flags & GF_ADDRES) {
                    size_t rx = (size_t)gm*ldr + gn;
                    v += (float)Rh[rx] + (float)Rl[rx];
                }
                if (flags & GF_ACCH)
                    v += (float)oh[ox] + (float)ol[ox];
                if (flags & GF_RELU_OUT) v = fmaxf(v, 0.f);
                if (flags & GF_GELU_OUT) v = 0.5f*v*(1.0f + erff(v*0.70710678118654752f));
                if (oh) {
                    _Float16 hv = (_Float16)v;
                    oh[ox] = hv;
                    ol[ox] = (_Float16)(v - (float)hv);
                } else {
                    C[ox] = v;
                }
            }
}

// ===================== fp32 GEMM (small head GEMM, N=122) =====================
#define BM 64
#define BN 64
#define BK 16
__global__ __launch_bounds__(256) void gemm_kernel(
    const float* __restrict__ A, int lda,
    const float* __restrict__ W, int ldb,
    float* __restrict__ C, int ldc,
    const float* __restrict__ bias,
    int M, int N, int K)
{
    __shared__ __align__(16) float As[BK][BM+4];
    __shared__ __align__(16) float Bs[BK][BN+4];
    int tid = threadIdx.x;
    int tx = tid & 15, ty = tid >> 4;
    int m0 = blockIdx.x * BM;
    int n0 = blockIdx.y * BN;
    float acc[4][4] = {};
    for (int k0 = 0; k0 < K; k0 += BK) {
        #pragma unroll
        for (int r = 0; r < 4; r++) {
            int li = tid + 256*r;
            int m  = li >> 4;
            int kk = li & 15;
            int gm = m0 + m, gk = k0 + kk;
            As[kk][m] = (gm < M && gk < K) ? A[(size_t)gm*lda + gk] : 0.f;
        }
        #pragma unroll
        for (int r = 0; r < 4; r++) {
            int li = tid + 256*r;
            int kk = li >> 6;
            int n  = li & 63;
            int gk = k0 + kk, gn = n0 + n;
            Bs[kk][n] = (gk < K && gn < N) ? W[(size_t)gk*ldb + gn] : 0.f;
        }
        __syncthreads();
        #pragma unroll
        for (int kk = 0; kk < BK; kk++) {
            float4 a  = *(const float4*)&As[kk][ty*4];
            float4 bb = *(const float4*)&Bs[kk][tx*4];
            float av[4] = {a.x, a.y, a.z, a.w};
            float bv[4] = {bb.x, bb.y, bb.z, bb.w};
            #pragma unroll
            for (int i = 0; i < 4; i++)
                #pragma unroll
                for (int j = 0; j < 4; j++)
                    acc[i][j] += av[i] * bv[j];
        }
        __syncthreads();
    }
    #pragma unroll
    for (int i = 0; i < 4; i++) {
        int gm = m0 + ty*4 + i;
        if (gm >= M) continue;
        #pragma unroll
        for (int j = 0; j < 4; j++) {
            int gn = n0 + tx*4 + j;
            if (gn >= N) continue;
            float v = acc[i][j];
            if (bias) v += bias[gn];
            C[(size_t)gm*ldc + gn] = v;
        }
    }
}

// ===================== MFMA attention =====================
__device__ inline int scidx(int row, int col) {
    return row*128 + (((col>>2) ^ (row&7))<<2) + (col&3);
}
__global__ __launch_bounds__(256) void attn2_kernel(
    const _Float16* __restrict__ QhG, const _Float16* __restrict__ QlG,
    const _Float16* __restrict__ KhG, const _Float16* __restrict__ KlG,
    const _Float16* __restrict__ VhG, const _Float16* __restrict__ VlG,
    const int* __restrict__ amask,
    _Float16* __restrict__ Ch, _Float16* __restrict__ Cl)
{
    __shared__ __align__(16) char smem[65536];
    _Float16* Qh_s = (_Float16*)smem;            // [64][72]
    _Float16* Ql_s = Qh_s + 64*72;
    _Float16* Kh_s = Ql_s + 64*72;               // [128][72]
    _Float16* Kl_s = Kh_s + 128*72;
    float*    Sc   = (float*)smem;               // [64][128] swizzled (phase 2)
    _Float16* Vth  = (_Float16*)(smem + 32768);  // [64][128] swizzled
    _Float16* Vtl  = Vth + 64*128;

    int blk = blockIdx.x;
    int qh2 = blk & 1;
    int bh  = blk >> 1;
    int b = bh / NH_, hh = bh % NH_;
    const int tid = threadIdx.x, lane = tid&63, wid = tid>>6;
    const int l15 = lane&15, quad = lane>>4;
    const int qr = wid*16;
    size_t tokb = (size_t)b*S_*H_ + (size_t)hh*DH_;

    float nmask[8];
    #pragma unroll
    for (int j = 0; j < 8; j++)
        nmask[j] = (amask[b*S_ + j*16 + l15] > 0) ? 0.f : -1e9f;

    {
        int row = tid>>2, part = (tid&3)*16;
        size_t qg = tokb + (size_t)(qh2*64 + row)*H_ + part;
        *(uint4*)&Qh_s[row*72 + part] = *(const uint4*)(QhG + qg);
        *(uint4*)&Ql_s[row*72 + part] = *(const uint4*)(QlG + qg);
        #pragma unroll
        for (int p = 0; p < 2; p++) {
            int krow = row + p*64;
            size_t kg = tokb + (size_t)krow*H_ + part;
            *(uint4*)&Kh_s[krow*72 + part] = *(const uint4*)(KhG + kg);
            *(uint4*)&Kl_s[krow*72 + part] = *(const uint4*)(KlG + kg);
        }
    }
    __syncthreads();

    f32x4 acc1[8];
    #pragma unroll
    for (int j = 0; j < 8; j++) acc1[j] = (f32x4){0.f,0.f,0.f,0.f};
    half8 aqh[2], aql[2];
    #pragma unroll
    for (int kc = 0; kc < 2; kc++) {
        aqh[kc] = *(const half8*)&Qh_s[(qr + l15)*72 + kc*32 + quad*8];
        aql[kc] = *(const half8*)&Ql_s[(qr + l15)*72 + kc*32 + quad*8];
    }
    #pragma unroll
    for (int j = 0; j < 8; j++) {
        #pragma unroll
        for (int kc = 0; kc < 2; kc++) {
            half8 bkh = *(const half8*)&Kh_s[(j*16 + l15)*72 + kc*32 + quad*8];
            half8 bkl = *(const half8*)&Kl_s[(j*16 + l15)*72 + kc*32 + quad*8];
            acc1[j] = __builtin_amdgcn_mfma_f32_16x16x32_f16(aqh[kc], bkh, acc1[j], 0,0,0);
            acc1[j] = __builtin_amdgcn_mfma_f32_16x16x32_f16(aqh[kc], bkl, acc1[j], 0,0,0);
            acc1[j] = __builtin_amdgcn_mfma_f32_16x16x32_f16(aql[kc], bkh, acc1[j], 0,0,0);
        }
    }
    __syncthreads();

    #pragma unroll
    for (int j = 0; j < 8; j++)
        #pragma unroll
        for (int r = 0; r < 4; r++) {
            int row = qr + quad*4 + r;
            int col = j*16 + l15;
            Sc[scidx(row, col)] = acc1[j][r]*INV_SQRT_DH + nmask[j];
        }
    {
        int key = tid>>1, dh = (tid&1)*32;
        union V32 { _Float16 h[32]; uint4 u[4]; } bufh, bufl;
        #pragma unroll
        for (int e = 0; e < 4; e++) {
            bufh.u[e] = *(const uint4*)(VhG + tokb + (size_t)key*H_ + dh + e*8);
            bufl.u[e] = *(const uint4*)(VlG + tokb + (size_t)key*H_ + dh + e*8);
        }
        int kg = key>>3, kr = key&7;
        #pragma unroll
        for (int e = 0; e < 32; e++) {
            int d = dh + e;
            int pos = kg ^ (d & 7);
            Vth[d*128 + pos*8 + kr] = bufh.h[e];
            Vtl[d*128 + pos*8 + kr] = bufl.h[e];
        }
    }
    __syncthreads();

    {
        int row = tid>>2, part = (tid&3)*32;
        float mx = -INFINITY;
        #pragma unroll 8
        for (int e = 0; e < 32; e++)
            mx = fmaxf(mx, Sc[scidx(row, part+e)]);
        mx = fmaxf(mx, __shfl_xor(mx, 1));
        mx = fmaxf(mx, __shfl_xor(mx, 2));
        float s = 0.f;
        #pragma unroll 8
        for (int e = 0; e < 32; e++) {
            int idx = scidx(row, part+e);
            float ev = expf(Sc[idx] - mx);
            Sc[idx] = ev; s += ev;
        }
        s += __shfl_xor(s, 1);
        s += __shfl_xor(s, 2);
        float inv = 1.0f / s;
        #pragma unroll 8
        for (int e = 0; e < 32; e++)
            Sc[scidx(row, part+e)] *= inv;
    }
    __syncthreads();

    f32x4 acc2[4];
    #pragma unroll
    for (int jd = 0; jd < 4; jd++) acc2[jd] = (f32x4){0.f,0.f,0.f,0.f};
    #pragma unroll
    for (int kc = 0; kc < 4; kc++) {
        int q = qr + l15;
        int g16 = kc*8 + quad*2;
        float4 p0 = *(const float4*)&Sc[q*128 + ((g16   ^ (q&7))<<2)];
        float4 p1 = *(const float4*)&Sc[q*128 + (((g16+1) ^ (q&7))<<2)];
        float pv[8] = {p0.x,p0.y,p0.z,p0.w, p1.x,p1.y,p1.z,p1.w};
        union U { _Float16 h[8]; half8 v; } ph, pl;
        #pragma unroll
        for (int e = 0; e < 8; e++) {
            _Float16 hv = (_Float16)pv[e];
            ph.h[e] = hv; pl.h[e] = (_Float16)(pv[e] - (float)hv);
        }
        #pragma unroll
        for (int jd = 0; jd < 4; jd++) {
            int n = jd*16 + l15;
            int pos = (kc*4 + quad) ^ (n & 7);
            half8 vh = *(const half8*)&Vth[n*128 + pos*8];
            half8 vl = *(const half8*)&Vtl[n*128 + pos*8];
            acc2[jd] = __builtin_amdgcn_mfma_f32_16x16x32_f16(ph.v, vh, acc2[jd], 0,0,0);
            acc2[jd] = __builtin_amdgcn_mfma_f32_16x16x32_f16(ph.v, vl, acc2[jd], 0,0,0);
            acc2[jd] = __builtin_amdgcn_mfma_f32_16x16x32_f16(pl.v, vh, acc2[jd], 0,0,0);
        }
    }
    #pragma unroll
    for (int jd = 0; jd < 4; jd++)
        #pragma unroll
        for (int r = 0; r < 4; r++) {
            int row = qr + quad*4 + r;
            int token = b*S_ + qh2*64 + row;
            int d = jd*16 + l15;
            float v = acc2[jd][r];
            _Float16 hv = (_Float16)v;
            Ch[(size_t)token*H_ + hh*DH_ + d] = hv;
            Cl[(size_t)token*H_ + hh*DH_ + d] = (_Float16)(v - (float)hv);
        }
}

// ===================== intent head =====================
__global__ __launch_bounds__(64) void intent_kernel(
    const _Float16* __restrict__ Xh, const _Float16* __restrict__ Xl,
    const float* __restrict__ iW1,
    const float* __restrict__ ib1, const float* __restrict__ iW2,
    const float* __restrict__ ib2, const int* __restrict__ tgt,
    float* __restrict__ iloss, float* __restrict__ outf)
{
    int b = blockIdx.x; int j = threadIdx.x;
    __shared__ float h1[64];
    __shared__ float lg[32];
    const _Float16* x0h = Xh + (size_t)b*S_*H_;
    const _Float16* x0l = Xl + (size_t)b*S_*H_;
    float acc = ib1[j];
    for (int h = 0; h < H_; h++) {
        float x = (float)x0h[h] + (float)x0l[h];
        acc += fmaxf(x, 0.f) * iW1[(size_t)h*64 + j];
    }
    h1[j] = fmaxf(acc, 0.f);
    __syncthreads();
    if (j < INTENT_) {
        float l = ib2[j];
        for (int k = 0; k < 64; k++) l += h1[k]*iW2[k*INTENT_ + j];
        lg[j] = l;
    }
    __syncthreads();
    if (j == 0) {
        float mx = -INFINITY; int bi = 0;
        for (int c = 0; c < INTENT_; c++) if (lg[c] > mx) { mx = lg[c]; bi = c; }
        float sm = 0.f;
        for (int c = 0; c < INTENT_; c++) sm += expf(lg[c]-mx);
        float lse = mx + logf(sm);
        iloss[b] = lse - lg[tgt[b]];
        outf[1 + (size_t)NT_ + b] = (float)bi;
    }
}

// ===================== fused CRF-llh + Viterbi =====================
// grid (64, 2): y=0 -> CRF llh for batch x ; y=1 -> Viterbi for batch x.
// 512 threads: j = tid>>2 (tag), p = tid&3 (i-partition, i = 4e+p).
#define VST 130
__global__ __launch_bounds__(512) void crf_vit_kernel(
    const float* __restrict__ E_, const int* __restrict__ tags,
    const int* __restrict__ mask, const float* __restrict__ start,
    const float* __restrict__ endv, const float* __restrict__ trans,
    float* __restrict__ crfv, unsigned char* __restrict__ BPg,
    float* __restrict__ outf)
{
    __shared__ __align__(16) float tT[TAGS_*VST];   // [j][i], stride 130
    __shared__ float alpha[TAGS_+2];
    __shared__ float ealpha[TAGS_+2];
    __shared__ float mxbuf[16];
    __shared__ int lastt;
    int b = blockIdx.x;
    int mode = blockIdx.y;
    int tid = threadIdx.x, lane = tid&63, wid = tid>>6;
    int j = tid>>2, p = tid&3;
    int cnt = (p < 2) ? 31 : 30;
    const float* E = E_ + (size_t)b*S_*TAGS_;

    if (j < TAGS_) {
        for (int e = 0; e < cnt; e++) {
            int i = 4*e + p;
            float tv = trans[i*TAGS_ + j];
            tT[j*VST + i] = mode ? tv : expf(tv);
        }
        if (p == 0) alpha[j] = start[j] + E[j];
    }
    __syncthreads();

    if (mode == 0) {
        // ---------- CRF log-likelihood ----------
        for (int t = 1; t < S_; t++) {
            if (wid == 0) {
                float a = (lane < TAGS_) ? alpha[lane] : -3e38f;
                if (lane + 64 < TAGS_) a = fmaxf(a, alpha[lane+64]);
                a = wave_max(a);
                if (lane == 0) mxbuf[0] = a;
            }
            __syncthreads();
            float mx = mxbuf[0];
            if (p == 0 && j < TAGS_) ealpha[j] = expf(alpha[j] - mx);
            __syncthreads();
            float s = 0.f;
            if (j < TAGS_) {
                const float* tr = &tT[j*VST];
                for (int e = 0; e < cnt; e++) {
                    int i = 4*e + p;
                    s += ealpha[i]*tr[i];
                }
            }
            s += __shfl_xor(s, 1);
            s += __shfl_xor(s, 2);
            int m_t = mask[b*S_ + t];
            float ee = (j < TAGS_) ? E[(size_t)t*TAGS_ + j] : 0.f;
            float nv = mx + logf(s) + ee;
            __syncthreads();
            if (p == 0 && j < TAGS_ && m_t) alpha[j] = nv;
            __syncthreads();
        }
        // numerator over timesteps (threads 0..127 handle t)
        float term = 0.f, mkf = 0.f;
        if (tid < S_) {
            int mk = mask[b*S_ + tid]; mkf = (float)mk;
            if (tid >= 1 && mk) {
                int tg = tags[b*S_ + tid], tgp = tags[b*S_ + tid - 1];
                term = trans[tgp*TAGS_ + tg] + E[(size_t)tid*TAGS_ + tg];
            }
        }
        if (wid < 2) {
            float ts = wave_sum(term);
            float ms = wave_sum(mkf);
            if (lane == 0) { mxbuf[2+wid] = ts; mxbuf[4+wid] = ms; }
        }
        __syncthreads();
        if (wid == 0) {
            float v1 = (lane < TAGS_) ? alpha[lane] + endv[lane] : -3e38f;
            float v2 = (lane+64 < TAGS_) ? alpha[lane+64] + endv[lane+64] : -3e38f;
            float m = wave_max(fmaxf(v1, v2));
            float sd = ((lane < TAGS_) ? expf(v1 - m) : 0.f)
                     + ((lane+64 < TAGS_) ? expf(v2 - m) : 0.f);
            sd = wave_sum(sd);
            if (lane == 0) {
                float denom = m + logf(sd);
                float numsum = mxbuf[2] + mxbuf[3];
                int msum = (int)(mxbuf[4] + mxbuf[5]);
                int tag0 = tags[b*S_];
                int last_tag = tags[b*S_ + (msum - 1)];
                float num = start[tag0] + E[tag0] + numsum + endv[last_tag];
                crfv[b] = num - denom;
            }
        }
    } else {
        // ---------- Viterbi ----------
        size_t bpb = (size_t)b*(S_-1)*TAGS_;
        for (int t = 1; t < S_; t++) {
            float best = -3e38f; int bi = 0;
            if (j < TAGS_) {
                const float* tr = &tT[j*VST];
                for (int e = 0; e < cnt; e++) {
                    int i = 4*e + p;
                    float v = alpha[i] + tr[i];
                    if (v > best) { best = v; bi = i; }
                }
            }
            {
                float ov = __shfl_xor(best, 1); int oi = __shfl_xor(bi, 1);
                if (ov > best || (ov == best && oi < bi)) { best = ov; bi = oi; }
                ov = __shfl_xor(best, 2); oi = __shfl_xor(bi, 2);
                if (ov > best || (ov == best && oi < bi)) { best = ov; bi = oi; }
            }
            int m_t = mask[b*S_ + t];
            float ee = (j < TAGS_) ? E[(size_t)t*TAGS_ + j] : 0.f;
            float nv; int nb;
            if (m_t) { nv = best + ee; nb = bi; }
            else     { nv = (j < TAGS_) ? alpha[j] : 0.f; nb = j; }
            __syncthreads();
            if (p == 0 && j < TAGS_) {
                alpha[j] = nv;
                BPg[bpb + (size_t)(t-1)*TAGS_ + j] = (unsigned char)nb;
            }
            __syncthreads();
        }
        if (wid == 0) {
            float v; int idx;
            float v1 = (lane < TAGS_) ? alpha[lane] + endv[lane] : -3e38f;
            float v2 = (lane+64 < TAGS_) ? alpha[lane+64] + endv[lane+64] : -3e38f;
            if (v2 > v1) { v = v2; idx = lane+64; } else { v = v1; idx = lane; }
            #pragma unroll
            for (int d = 32; d; d >>= 1) {
                float ov = __shfl_xor(v, d); int oi = __shfl_xor(idx, d);
                if (ov > v || (ov == v && oi < idx)) { v = ov; idx = oi; }
            }
            if (lane == 0) lastt = idx;
        }
        __syncthreads();
        unsigned char* bpl = (unsigned char*)tT;
        for (int o = tid; o < (S_-1)*TAGS_; o += 512)
            bpl[o] = BPg[bpb + o];
        __syncthreads();
        if (tid == 0) {
            int tag = lastt;
            outf[1 + (size_t)b*S_ + (S_-1)] = (float)tag;
            for (int t = S_-1; t >= 1; t--) {
                tag = bpl[(t-1)*TAGS_ + tag];
                outf[1 + (size_t)b*S_ + (t-1)] = (float)tag;
            }
        }
    }
}

// ===================== final joint loss =====================
__global__ void combine_kernel(const float* __restrict__ iloss,
                               const float* __restrict__ crfv,
                               const float* __restrict__ lv,
                               float* __restrict__ outf)
{
    if (threadIdx.x == 0 && blockIdx.x == 0) {
        float si = 0.f, sc = 0.f;
        for (int b = 0; b < B_; b++) { si += iloss[b]; sc += crfv[b]; }
        float p1 = expf(-lv[0]), p2 = expf(-lv[1]);
        float slots_loss = -sc;
        outf[0] = p1*si + (float)B_*lv[0] + p2*slots_loss + lv[1];
    }
}

// ===================== host launch =====================
extern "C" void kernel_launch(void* const* d_in, const int* in_sizes, int n_in,
                              void* d_out, int out_size, void* d_ws, size_t ws_size,
                              hipStream_t stream) {
    const int*   ids   = (const int*)  d_in[0];
    const int*   amask = (const int*)  d_in[1];
    const int*   itgt  = (const int*)  d_in[2];
    const int*   stgt  = (const int*)  d_in[3];
    const int*   smask = (const int*)  d_in[4];
    const float* we    = (const float*)d_in[5];
    const float* pe    = (const float*)d_in[6];
    const float* embs  = (const float*)d_in[7];
    const float* embb  = (const float*)d_in[8];
    const float* Wq    = (const float*)d_in[9];
    const float* bq    = (const float*)d_in[10];
    const float* Wk    = (const float*)d_in[11];
    const float* bk    = (const float*)d_in[12];
    const float* Wv    = (const float*)d_in[13];
    const float* bv    = (const float*)d_in[14];
    const float* Wo    = (const float*)d_in[15];
    const float* bo    = (const float*)d_in[16];
    const float* sas   = (const float*)d_in[17];
    const float* sab   = (const float*)d_in[18];
    const float* W1f   = (const float*)d_in[19];
    const float* b1f   = (const float*)d_in[20];
    const float* W2f   = (const float*)d_in[21];
    const float* b2f   = (const float*)d_in[22];
    const float* ols   = (const float*)d_in[23];
    const float* olb   = (const float*)d_in[24];
    const float* iW1   = (const float*)d_in[25];
    const float* ib1   = (const float*)d_in[26];
    const float* iW2   = (const float*)d_in[27];
    const float* ib2   = (const float*)d_in[28];
    const float* sW1   = (const float*)d_in[29];
    const float* sb1   = (const float*)d_in[30];
    const float* sW2   = (const float*)d_in[31];
    const float* sb2   = (const float*)d_in[32];
    const float* crfs  = (const float*)d_in[33];
    const float* crfe  = (const float*)d_in[34];
    const float* crft  = (const float*)d_in[35];
    const float* lv    = (const float*)d_in[36];

    float* outf = (float*)d_out;
    float* wsf  = (float*)d_ws;
    const long NTHh = (long)NT_ * H_;        // 6,291,456 (halves per tensor)
    const long NBf  = NTHh;                  // floats per fp32-equivalent tensor
    const long HH   = (long)H_ * H_;         // 589,824

    // layout (floats): [XhXl: NBf][P: 3*NBf][ChCl: NBf][WA][WB1][WB2][misc]
    _Float16* Xh = (_Float16*)wsf;
    _Float16* Xl = Xh + NTHh;
    float*    Pf = wsf + NBf;
    _Float16* Ph = (_Float16*)Pf;
    _Float16 *Qh = Ph, *Ql = Ph + NTHh, *Kh = Ph + 2*NTHh, *Kl = Ph + 3*NTHh,
             *Vh = Ph + 4*NTHh, *Vl = Ph + 5*NTHh;
    _Float16 *Sh = Ph, *Sl = Ph + NTHh;                 // sum halves (reuse Q slot)
    _Float16* Fh = (_Float16*)(wsf + 2*NBf);            // FF intermediate hi
    _Float16* Fl = (_Float16*)(wsf + 3*NBf);            // FF intermediate lo
    _Float16* Ch = (_Float16*)(wsf + 4*NBf);
    _Float16* Cl = Ch + NTHh;
    const long wa0 = 5*NBf;
    _Float16* WAh = (_Float16*)(wsf + wa0);             // 8*HH halves (QKVO hi+lo)
    _Float16* WAl = WAh + 4*HH;
    const long wb1 = wa0 + 2359296;
    _Float16* WB1h = (_Float16*)(wsf + wb1);
    _Float16* WB1l = WB1h + 2359296;
    const long wb2 = wb1 + 2359296;
    _Float16* WB2h = (_Float16*)(wsf + wb2);
    _Float16* WB2l = WB2h + 2359296;
    float* iloss = wsf + wb2 + 2359296;
    float* crfv  = iloss + 64;
    // heads scratch in P region (free after encoder)
    float* H1 = Pf;                                     // 8192*256
    float* logits = Pf + 2097152;                       // 8192*122
    unsigned char* BPg = (unsigned char*)(Pf + 2097152 + 999424);

    auto g3 = [&](int gy, int gz,
                  const _Float16* A_h, const _Float16* A_l, int lda,
                  const _Float16* WtH, const _Float16* WtL, int ldw, long wz,
                  float* C, _Float16* OH, _Float16* OL, int ldc, long oz,
                  const _Float16* Rh, const _Float16* Rl,
                  const float* b0, const float* b1_, const float* b2_,
                  int K, int flags) {
        hipLaunchKernelGGL(gemm3_kernel, dim3(NT_/128, gy, gz), dim3(256), 0, stream,
                           A_h, A_l, lda, WtH, WtL, ldw, wz,
                           C, OH, OL, ldc, oz, Rh, Rl, H_, b0, b1_, b2_, K, flags);
    };

    hipLaunchKernelGGL(embed_ln_kernel, dim3(NT_), dim3(256), 0, stream,
                       ids, we, pe, embs, embb, Xh, Xl);

    for (int i = 0; i < L_; i++) {
        const long WO = (long)i*HH;
        // QKV+O weights -> WA (z=4)
        hipLaunchKernelGGL(wconv_kernel, dim3(12,12,4), dim3(256), 0, stream,
                           Wq+WO, Wk+WO, Wv+WO, Wo+WO, H_, H_, WAh, WAl, HH);
        // QKV (z=3)
        g3(6, 3, Xh, Xl, H_, WAh, WAl, H_, HH,
           nullptr, Ph, Ph+NTHh, H_, 2*NTHh, nullptr, nullptr,
           bq+i*H_, bk+i*H_, bv+i*H_, H_, 0);
        // attention
        hipLaunchKernelGGL(attn2_kernel, dim3(B_*NH_*2), dim3(256), 0, stream,
                           Qh, Ql, Kh, Kl, Vh, Vl, amask, Ch, Cl);
        // O-proj + residual -> sum halves (Sh/Sl)
        g3(6, 1, Ch, Cl, H_, WAh+3*HH, WAl+3*HH, H_, 0,
           nullptr, Sh, Sl, H_, 0, Xh, Xl,
           bo+i*H_, nullptr, nullptr, H_, GF_ADDRES);
        hipLaunchKernelGGL(ln2_kernel, dim3(NT_), dim3(384), 0, stream,
                           Sh, Sl, sas+i*H_, sab+i*H_, Xh, Xl,
                           (_Float16*)nullptr, (_Float16*)nullptr);
        // FF weights
        hipLaunchKernelGGL(wconv_kernel, dim3(12,48,1), dim3(256), 0, stream,
                           W1f+(long)i*H_*FF_, nullptr, nullptr, nullptr,
                           H_, FF_, WB1h, WB1l, 0);
        hipLaunchKernelGGL(wconv_kernel, dim3(48,12,1), dim3(256), 0, stream,
                           W2f+(long)i*FF_*H_, nullptr, nullptr, nullptr,
                           FF_, H_, WB2h, WB2l, 0);
        for (int c = 0; c < 2; c++) {
            const int CW = FF_/2;  // 1536
            g3(12, 1, Xh, Xl, H_,
               WB1h+(long)c*CW*H_, WB1l+(long)c*CW*H_, H_, 0,
               nullptr, Fh, Fl, CW, 0, nullptr, nullptr,
               b1f+(long)i*FF_+c*CW, nullptr, nullptr, H_, GF_GELU_OUT);
            g3(6, 1, Fh, Fl, CW,
               WB2h+(long)c*CW, WB2l+(long)c*CW, FF_, 0,
               nullptr, Sh, Sl, H_, 0, Xh, Xl,
               (c==0) ? (b2f+i*H_) : nullptr, nullptr, nullptr,
               CW, (c==0) ? GF_ADDRES : GF_ACCH);
        }
        hipLaunchKernelGGL(ln2_kernel, dim3(NT_), dim3(384), 0, stream,
                           Sh, Sl, ols+i*H_, olb+i*H_, Xh, Xl,
                           (i==L_-1) ? Ch : (_Float16*)nullptr,
                           (i==L_-1) ? Cl : (_Float16*)nullptr);
    }

    hipLaunchKernelGGL(intent_kernel, dim3(B_), dim3(64), 0, stream,
                       Xh, Xl, iW1, ib1, iW2, ib2, itgt, iloss, outf);

    // slots head: H1 = relu(relu(x)@sW1 + sb1)  (relu(x) halves are in Ch/Cl)
    hipLaunchKernelGGL(wconv_kernel, dim3(12,4,1), dim3(256), 0, stream,
                       sW1, nullptr, nullptr, nullptr, H_, 256,
                       WAh, WAh + (long)256*H_, 0);
    g3(2, 1, Ch, Cl, H_, WAh, WAh + (long)256*H_, H_, 0,
       H1, nullptr, nullptr, 256, 0, nullptr, nullptr,
       sb1, nullptr, nullptr, H_, GF_RELU_OUT);
    hipLaunchKernelGGL(gemm_kernel, dim3(NT_/BM, 2), dim3(256), 0, stream,
                       H1, 256, sW2, TAGS_, logits, TAGS_, sb2, NT_, TAGS_, 256);

    hipLaunchKernelGGL(crf_vit_kernel, dim3(B_, 2), dim3(512), 0, stream,
                       logits, stgt, smask, crfs, crfe, crft, crfv, BPg, outf);

    hipLaunchKernelGGL(combine_kernel, dim3(1), dim3(64), 0, stream,
                       iloss, crfv, lv, outf);
}